// Round 8
// baseline (1150.305 us; speedup 1.0000x reference)
//
#include <hip/hip_runtime.h>
#include <math.h>

#define TT 32
#define MAXREC 8

// workspace byte offsets
#define OFF_ZBUF   0u          // 128*128 f32 = 65536
#define OFF_KEYS   65536u      // 256*128 u64 = 262144
#define OFF_ESQ    327680u     // 8192 f32 = 32768
#define OFF_GW     360448u     // 128*128 f32 = 65536
#define OFF_PANG   425984u     // 128*64 f32 = 32768
#define OFF_MEMR   458752u     // 128*32*64 f32 = 1048576
#define OFF_MEMI   1507328u    // 1048576
#define OFF_OUTH   2555904u    // 4096*128 f32 = 2097152
#define OFF_RST    4653056u    // 128*4 f32 = 2048
#define OFF_FINF   4655104u    // 128 u64 (fallback exchange)

#define LOGN 33554432u         // 128*32*8192
#define TWO_PI_F 6.283185307179586f

typedef unsigned long long u64;

__device__ __forceinline__ float wredsum(float v) {
#pragma unroll
  for (int m = 32; m > 0; m >>= 1) v += __shfl_xor(v, m);
  return v;
}
__device__ __forceinline__ u64 shflx64(u64 v, int m) {
  int lo = __shfl_xor((int)(unsigned)(v & 0xffffffffull), m);
  int hi = __shfl_xor((int)(unsigned)(v >> 32), m);
  return ((u64)(unsigned)hi << 32) | (unsigned)lo;
}
// monotone float->u32 + idx: u64-min == (min dist, then min idx) == jnp.argmin tie-break
__device__ __forceinline__ u64 packkey(float d, unsigned c) {
  unsigned u = __float_as_uint(d);
  u = (u & 0x80000000u) ? ~u : (u | 0x80000000u);
  return ((u64)u << 32) | c;
}
__device__ __forceinline__ float unpackd2(u64 key) {
  unsigned hi = (unsigned)(key >> 32);
  unsigned orig = (hi & 0x80000000u) ? (hi & 0x7fffffffu) : ~hi;
  return __uint_as_float(orig);
}
// coherent helpers (fallback path only)
__device__ __forceinline__ u64 ld_coh64(const u64* p) {
  u64 v;
  asm volatile("global_load_dwordx2 %0, %1, off sc0 sc1\n\ts_waitcnt vmcnt(0)"
               : "=&v"(v) : "v"(p) : "memory");
  return v;
}
__device__ __forceinline__ void st_coh64(u64* p, u64 v) {
  asm volatile("global_store_dwordx2 %0, %1, off sc0 sc1\n\ts_waitcnt vmcnt(0)"
               :: "v"(p), "v"(v) : "memory");
}

// ================= K0: init =================
__global__ __launch_bounds__(256) void k_init(
    const int* __restrict__ x_seq, const float* __restrict__ enc,
    const float* __restrict__ vqe, const float* __restrict__ nrg,
    const float* __restrict__ nrb, const float* __restrict__ nig,
    const float* __restrict__ nib, const float* __restrict__ igp,
    char* __restrict__ ws)
{
  float* zbuf = (float*)(ws + OFF_ZBUF);
  float* esqG = (float*)(ws + OFF_ESQ);
  float* gwG  = (float*)(ws + OFF_GW);
  float* pangG= (float*)(ws + OFF_PANG);
  float* memR = (float*)(ws + OFF_MEMR);
  float* memI = (float*)(ws + OFF_MEMI);
  float* rstG = (float*)(ws + OFF_RST);
  u64*   finF = (u64*)(ws + OFF_FINF);
  const int r = blockIdx.x, tid = threadIdx.x;
  float4 z4 = {0.f, 0.f, 0.f, 0.f};
  for (int i = tid; i < 512; i += 256) {
    ((float4*)(memR + (size_t)r * 2048))[i] = z4;
    ((float4*)(memI + (size_t)r * 2048))[i] = z4;
  }
  if (tid < 4) rstG[r * 4 + tid] = 0.f;
  if (tid == 0) finF[r] = 0ull;
  __shared__ float ep[64][4];
  {
    int c = tid >> 2, q = tid & 3;
    const float4* e = (const float4*)(vqe + ((size_t)(r * 64 + c) << 7)) + q * 8;
    float s = 0.f;
#pragma unroll
    for (int j = 0; j < 8; ++j) {
      float4 v = e[j];
      s = fmaf(v.x, v.x, fmaf(v.y, v.y, fmaf(v.z, v.z, fmaf(v.w, v.w, s))));
    }
    ep[c][q] = s;
  }
  __shared__ float g[128];
  const float alpha = 1.0f / (1.0f + expf(-igp[0]));
  const float onema = 1.0f - alpha;
  int tok = x_seq[r * TT];
  if (tid < 128) {
    float gv = onema * enc[((size_t)tok << 7) + tid];
    g[tid] = gv;
    gwG[r * 128 + tid] = gv;
  }
  __syncthreads();
  if (tid < 64) esqG[r * 64 + tid] = ep[tid][0] + ep[tid][1] + ep[tid][2] + ep[tid][3];
  if (tid < 64) pangG[r * 64 + tid] = atan2f(g[64 + tid], g[tid]);
  if (tid < 128) {
    float lnG = (tid < 64) ? nrg[tid] : nig[tid - 64];
    float lnB = (tid < 64) ? nrb[tid] : nib[tid - 64];
    float val = g[tid];
    float mu = wredsum(val) * 0.015625f;
    float xc = val - mu;
    float vr = wredsum(xc * xc) * 0.015625f;
    zbuf[r * 128 + tid] = xc * (1.0f / sqrtf(vr + 1e-5f)) * lnG + lnB;
  }
}

// ================= K1: pure VQ (256 blocks x 32 codes) =================
__global__ __launch_bounds__(256) void k_vq(const float* __restrict__ vqe,
                                            char* __restrict__ ws)
{
  const float* zbuf = (const float*)(ws + OFF_ZBUF);
  const float* esqG = (const float*)(ws + OFF_ESQ);
  u64* keys = (u64*)(ws + OFF_KEYS);
  const int s = blockIdx.x, tid = threadIdx.x;
  __shared__ float els[32 * 128];
  __shared__ float zloc[128 * 128];
  __shared__ float z2L[128];
  __shared__ float esqL[32];
  __shared__ u64 vtmp[128 * 9];
#pragma unroll
  for (int j = 0; j < 4; ++j) {
    int f4 = tid + j * 256;
    int c = f4 >> 5, k4 = f4 & 31;
    float4 v = *(const float4*)&vqe[((size_t)(s * 32 + c) << 7) + (k4 << 2)];
    *(float4*)&els[(c << 7) + ((k4 ^ c) << 2)] = v;
  }
#pragma unroll
  for (int j = 0; j < 16; ++j) {
    int f4 = tid + j * 256;
    int row = f4 >> 5, k4 = f4 & 31;
    float4 v = *(const float4*)&zbuf[f4 << 2];
    *(float4*)&zloc[(row << 7) + ((k4 ^ (row & 31)) << 2)] = v;
  }
  if (tid < 32) esqL[tid] = esqG[s * 32 + tid];
  __syncthreads();
  if (tid < 128) {
    float sm = 0.f;
#pragma unroll 8
    for (int k4 = 0; k4 < 32; ++k4) {
      float4 q = *(const float4*)&zloc[(tid << 7) + ((k4 ^ (tid & 31)) << 2)];
      sm = fmaf(q.x, q.x, fmaf(q.y, q.y, fmaf(q.z, q.z, fmaf(q.w, q.w, sm))));
    }
    z2L[tid] = sm;
  }
  const int rt = tid & 31, ct = tid >> 5;   // ct 0..7, codes ct*4..+3
  float acc[4][4];
#pragma unroll
  for (int rr = 0; rr < 4; ++rr)
#pragma unroll
    for (int cc = 0; cc < 4; ++cc) acc[rr][cc] = 0.f;
#pragma unroll 2
  for (int k4 = 0; k4 < 32; ++k4) {
    float4 zv[4], ev[4];
#pragma unroll
    for (int rr = 0; rr < 4; ++rr)
      zv[rr] = *(const float4*)&zloc[((rt + rr * 32) << 7) + ((k4 ^ rt) << 2)];
#pragma unroll
    for (int cc = 0; cc < 4; ++cc) {
      int cl = ct * 4 + cc;
      ev[cc] = *(const float4*)&els[(cl << 7) + ((k4 ^ cl) << 2)];
    }
#pragma unroll
    for (int rr = 0; rr < 4; ++rr)
#pragma unroll
      for (int cc = 0; cc < 4; ++cc)
        acc[rr][cc] = fmaf(zv[rr].x, ev[cc].x, fmaf(zv[rr].y, ev[cc].y,
                      fmaf(zv[rr].z, ev[cc].z, fmaf(zv[rr].w, ev[cc].w, acc[rr][cc]))));
  }
  __syncthreads();   // z2L ready for all waves
#pragma unroll
  for (int rr = 0; rr < 4; ++rr) {
    const int row = rt + rr * 32;
    const float z2r = z2L[row];
    u64 key = ~0ull;
#pragma unroll
    for (int cc = 0; cc < 4; ++cc) {
      int cl = ct * 4 + cc;
      float d2 = (z2r - 2.0f * acc[rr][cc]) + esqL[cl];
      u64 pk = packkey(d2, (unsigned)(s * 32 + cl));
      if (pk < key) key = pk;
    }
    vtmp[row * 9 + ct] = key;
  }
  __syncthreads();
  if (tid < 128) {
    u64 kmin = vtmp[tid * 9];
#pragma unroll
    for (int w = 1; w < 8; ++w) { u64 o = vtmp[tid * 9 + w]; if (o < kmin) kmin = o; }
    keys[(size_t)s * 128 + tid] = kmin;
  }
}

// ================= K2: row update (128 blocks) =================
__global__ __launch_bounds__(256) void k_row(
    const int* __restrict__ x_seq, const float* __restrict__ enc,
    const float* __restrict__ vqe,
    const float* __restrict__ nrg, const float* __restrict__ nrb,
    const float* __restrict__ nig, const float* __restrict__ nib,
    const float* __restrict__ qWr, const float* __restrict__ qbr,
    const float* __restrict__ qWi, const float* __restrict__ qbi,
    const float* __restrict__ gtw, const float* __restrict__ gtb,
    const float* __restrict__ aW, const float* __restrict__ ab,
    const float* __restrict__ hbp, const float* __restrict__ igp,
    float* __restrict__ dout, char* __restrict__ ws, int t)
{
  float* zbuf = (float*)(ws + OFF_ZBUF);
  const u64* keys = (const u64*)(ws + OFF_KEYS);
  const float* esqG = (const float*)(ws + OFF_ESQ);
  float* gwG  = (float*)(ws + OFF_GW);
  float* pangG= (float*)(ws + OFF_PANG);
  float* memR = (float*)(ws + OFF_MEMR);
  float* memI = (float*)(ws + OFF_MEMI);
  float* outh = (float*)(ws + OFF_OUTH);
  float* rstG = (float*)(ws + OFF_RST);
  u64*   finF = (u64*)(ws + OFF_FINF);

  const int r = blockIdx.x, tid = threadIdx.x;
  const int wv = tid >> 6;

  __shared__ __align__(16) float zfmL[128];
  __shared__ float gwrL[128], pangL[64], zqL[128];
  __shared__ float qkL[6][64], simL[32], attnL[32], mrL[64], miL[64];
  __shared__ unsigned idxL[128];
  __shared__ u64 key128L[128], km2[128][2];
  __shared__ float scalL[8], entpL[2], vqpL[2], wsumL[2], z2h[2];
  __shared__ float accv[4];
  __shared__ float dmeanS;
  __shared__ u64 actM[2], actN[2], ownkeyS, fbw[4];
  __shared__ unsigned pollOK, mfS;

  const float alpha = 1.0f / (1.0f + expf(-igp[0]));
  const float onema = 1.0f - alpha;
  const float hbias = log1pf(expf(hbp[0]));
  const float gtb0 = gtb[0];

  if (tid < 128) { zfmL[tid] = zbuf[r * 128 + tid]; gwrL[tid] = gwG[r * 128 + tid]; }
  if (tid < 64) pangL[tid] = pangG[r * 64 + tid];
  if (tid < 4) accv[tid] = 0.f;
  if (tid < 2) actM[tid] = ~0ull;
  __syncthreads();
  // gather all keys: thread (rr, half) scans 128 slices
  {
    const int rr = tid & 127, half = tid >> 7;
    u64 m = ~0ull;
    const u64* kp = keys + (size_t)(half * 128) * 128 + rr;
#pragma unroll 4
    for (int s = 0; s < 128; ++s) { u64 v = kp[(size_t)s * 128]; if (v < m) m = v; }
    km2[rr][half] = m;
  }
  __syncthreads();
  if (tid < 128) {
    u64 a = km2[tid][0], b = km2[tid][1];
    key128L[tid] = (a < b) ? a : b;
  }
  __syncthreads();

  int itv = 0;
  bool anyAct;
  for (;;) {
    // ---- consensus ----
    if (tid < 128) {
      u64 key = key128L[tid];
      idxL[tid] = (unsigned)key & 0xFFFFu;
      float d2 = unpackd2(key);
      bool act_b = ((actM[tid >> 6] >> (tid & 63)) & 1ull) != 0ull;
      bool stop = (1.25f * 0.0078125f * d2) < hbias;
      u64 ball = __ballot(act_b && !stop);
      if ((tid & 63) == 0) actN[tid >> 6] = ball;
    }
    __syncthreads();
    if (tid == 0) mfS = (unsigned)((actM[r >> 6] >> (r & 63)) & 1ull);
    if (tid < 2) actM[tid] = actN[tid];
    __syncthreads();
    anyAct = (actN[0] | actN[1]) != 0ull;
    const bool mf = mfS != 0u;
    const unsigned ii = idxL[r];
    // ---- entropy (waves 0-1) || zq + vq partials (waves 2-3) ----
    if (tid < 128) {
      unsigned my = idxL[tid];
      int c = 0;
#pragma unroll
      for (int j4 = 0; j4 < 32; ++j4) {
        uint4 q = *(const uint4*)&idxL[j4 * 4];
        c += (q.x == my) + (q.y == my) + (q.z == my) + (q.w == my);
      }
      float term = -0.0078125f * logf((float)c * 0.0078125f + 1e-10f);
      term = wredsum(term);
      if ((tid & 63) == 0) entpL[wv] = term;
    } else {
      const int d = tid - 128;
      float zq = vqe[((size_t)ii << 7) + d];
      zqL[d] = zq;
      float df = zq - zfmL[d];
      float sm = wredsum(df * df);
      if ((tid & 63) == 0) vqpL[wv - 2] = sm;
    }
    __syncthreads();
    // ---- P1: clin | sim | arb ----
    if (tid < 192) {
      const int h = tid >> 6, j = tid & 63;
      const float* wr = qWr + h * 4096 + j * 64;
      const float* wi = qWi + h * 4096 + j * 64;
      float da = 0.f, db_ = 0.f, dc = 0.f, de = 0.f;
#pragma unroll 4
      for (int d4 = 0; d4 < 64; d4 += 4) {
        float4 wrv = *(const float4*)&wr[d4];
        float4 wiv = *(const float4*)&wi[d4];
        float4 crv = *(const float4*)&zfmL[d4];
        float4 civ = *(const float4*)&zfmL[64 + d4];
        da = fmaf(crv.x, wrv.x, fmaf(crv.y, wrv.y, fmaf(crv.z, wrv.z, fmaf(crv.w, wrv.w, da))));
        db_ = fmaf(civ.x, wiv.x, fmaf(civ.y, wiv.y, fmaf(civ.z, wiv.z, fmaf(civ.w, wiv.w, db_))));
        dc = fmaf(civ.x, wrv.x, fmaf(civ.y, wrv.y, fmaf(civ.z, wrv.z, fmaf(civ.w, wrv.w, dc))));
        de = fmaf(crv.x, wiv.x, fmaf(crv.y, wiv.y, fmaf(crv.z, wiv.z, fmaf(crv.w, wiv.w, de))));
      }
      float brv = qbr[h * 64 + j], biv = qbi[h * 64 + j];
      qkL[2 * h][j] = da + brv - db_ - biv;
      qkL[2 * h + 1][j] = dc + brv + de + biv;
    } else if (tid < 224) {
      const int s2 = tid - 192;
      const float* mr = memR + (size_t)r * 2048 + s2 * 64;
      const float* mi = memI + (size_t)r * 2048 + s2 * 64;
      float a2 = 0.f;
      for (int d = 0; d < 64; ++d)
        a2 = fmaf(mr[d], zfmL[d], fmaf(mi[d], zfmL[64 + d], a2));
      simL[s2] = a2;
    } else if (tid < 227) {
      const int h = tid - 224;
      float a2 = ab[h];
      for (int k2 = 0; k2 < 128; ++k2) a2 = fmaf(zfmL[k2], aW[h * 128 + k2], a2);
      scalL[3 + h] = a2;
    }
    __syncthreads();
    // ---- gate | attn softmax | arb softmax | scalar combine ----
    if (tid < 64) {
      float p = fmaf(qkL[0][tid], qkL[2][tid], qkL[1][tid] * qkL[3][tid]);
      p = wredsum(p);
      if (tid == 0) scalL[0] = 1.0f / (1.0f + expf(-p));
    } else if (tid < 96) {
      const int s2 = tid - 64;
      float v = simL[s2];
      float m = v;
#pragma unroll
      for (int msk = 16; msk > 0; msk >>= 1) m = fmaxf(m, __shfl_xor(m, msk));
      float e = expf(v - m);
      float ss = e;
#pragma unroll
      for (int msk = 16; msk > 0; msk >>= 1) ss += __shfl_xor(ss, msk);
      attnL[s2] = e / ss;
    } else if (tid == 96) {
      float a0 = scalL[3], a1 = scalL[4], a2 = scalL[5];
      float m = fmaxf(a0, fmaxf(a1, a2));
      float e0 = expf(a0 - m), e1 = expf(a1 - m), e2 = expf(a2 - m);
      float ssum = e0 + e1 + e2;
      scalL[3] = e0 / ssum; scalL[4] = e1 / ssum; scalL[5] = e2 / ssum;
    } else if (tid == 97) {
      scalL[1] = 1.25f * (vqpL[0] + vqpL[1]) * 0.0078125f;
      scalL[2] = entpL[0] + entpL[1];
    }
    __syncthreads();
    // ---- attention readout ----
    if (tid < 128) {
      const int d = tid & 63;
      const float* ml = ((wv == 0) ? memR : memI) + (size_t)r * 2048;
      float a2 = 0.f;
#pragma unroll 4
      for (int s2 = 0; s2 < 32; ++s2) a2 = fmaf(attnL[s2], ml[s2 * 64 + d], a2);
      if (wv == 0) mrL[d] = a2; else miL[d] = a2;
    }
    __syncthreads();
    // ---- candidate + phase diff ----
    if (tid < 64) {
      const int d = tid;
      float gate = scalL[0], g0 = scalL[3], g1 = scalL[4], g2 = scalL[5];
      float cr = zfmL[d], ci = zfmL[64 + d];
      float ur = fmaf(g0, qkL[4][d] * gate, fmaf(g1, mrL[d], g2 * zqL[d]));
      float ui = fmaf(g0, qkL[5][d] * gate, fmaf(g1, miL[d], g2 * zqL[64 + d]));
      float cdr = fmaf(0.4f, ur, 0.6f * cr);
      float cdi = fmaf(0.4f, ui, 0.6f * ci);
      float ang = atan2f(cdi, cdr);
      float df = fabsf(ang - pangL[d]);
      df = fminf(df, TWO_PI_F - df);
      pangL[d] = ang;
      float dm = wredsum(df) * 0.015625f;
      if (mf) { gwrL[d] = cdr; gwrL[64 + d] = cdi; }
      if (d == 0) dmeanS = dm;
    }
    __syncthreads();
    if (tid == 0) {
      float aold = mf ? 1.0f : 0.0f;
      accv[3] += aold * dmeanS;
      accv[2] += aold * 0.01f;
      if (mf) {
        accv[0] = scalL[1];
        accv[1] = scalL[2];
        dout[(size_t)LOGN + 4 + (size_t)r * TT + t] = (float)ii;
      }
    }
    ++itv;
    if (!anyAct || itv >= MAXREC) break;
    // ======== fallback (never taken for this data; correct multi-iteration path) ========
    __syncthreads();
    const bool myact = ((actM[r >> 6] >> (r & 63)) & 1ull) != 0ull;
    if (myact) {
      if (tid < 128) {
        float lnG = (tid < 64) ? nrg[tid] : nig[tid - 64];
        float lnB = (tid < 64) ? nrb[tid] : nib[tid - 64];
        float val = gwrL[tid];
        float mu = wredsum(val) * 0.015625f;
        float xc = val - mu;
        float vr = wredsum(xc * xc) * 0.015625f;
        zfmL[tid] = xc * (1.0f / sqrtf(vr + 1e-5f)) * lnG + lnB;
      }
      __syncthreads();
      if (tid < 128) {
        float sq = zfmL[tid] * zfmL[tid];
        float sm = wredsum(sq);
        if ((tid & 63) == 0) z2h[wv] = sm;
      }
      __syncthreads();
      float z2own = z2h[0] + z2h[1];
      u64 km = ~0ull;
      for (int c = tid; c < 8192; c += 256) {
        const float4* e = (const float4*)(vqe + ((size_t)c << 7));
        float dot = 0.f;
#pragma unroll 8
        for (int k4 = 0; k4 < 32; ++k4) {
          float4 ev = e[k4];
          float4 zv = *(const float4*)&zfmL[k4 * 4];
          dot = fmaf(zv.x, ev.x, fmaf(zv.y, ev.y, fmaf(zv.z, ev.z, fmaf(zv.w, ev.w, dot))));
        }
        float d2 = z2own - 2.0f * dot + esqG[c];
        u64 pk = packkey(d2, (unsigned)c);
        if (pk < km) km = pk;
      }
#pragma unroll
      for (int m2 = 32; m2 > 0; m2 >>= 1) { u64 o = shflx64(km, m2); if (o < km) km = o; }
      if ((tid & 63) == 0) fbw[wv] = km;
      __syncthreads();
      if (tid == 0) {
        u64 kk = fbw[0];
        for (int w = 1; w < 4; ++w) if (fbw[w] < kk) kk = fbw[w];
        ownkeyS = kk;
      }
      __syncthreads();
    } else {
      __syncthreads();
    }
    {
      const unsigned tag = (unsigned)(((t << 3) | itv) & 0xFF);
      if (tid == 0) {
        u64 pub = myact ? ownkeyS : key128L[r];
        pub = (pub & 0xFFFFFFFFFF00FFFFull) | ((u64)tag << 16);
        st_coh64(&finF[r], pub);
      }
      while (true) {
        if (tid == 0) pollOK = 1u;
        __syncthreads();
        u64 v = 0;
        if (tid < 128) {
          v = ld_coh64(&finF[tid]);
          if ((unsigned)((v >> 16) & 0xFFull) != tag) pollOK = 0u;
        }
        __syncthreads();
        if (pollOK) { if (tid < 128) key128L[tid] = v; break; }
        __builtin_amdgcn_s_sleep(1);
      }
      __syncthreads();
    }
  } // iteration loop
  __syncthreads();
  // ======== tail: outh, mem_write, merge(t+1), LN -> z(t+1) ========
  if (tid < 128) outh[((size_t)r * TT + t) * 128 + tid] = gwrL[tid];
  if (tid < 4) rstG[r * 4 + tid] += accv[tid];
  if (t < TT - 1) {
    if (tid < 128) {
      float part = wredsum(gwrL[tid] * gtw[tid]);
      if ((tid & 63) == 0) wsumL[wv] = part;
    }
    __syncthreads();
    if (tid < 128) {
      float wg = 1.0f / (1.0f + expf(-(wsumL[0] + wsumL[1] + gtb0)));
      int slot = 31 - t;
      float* m = (tid < 64) ? &memR[(size_t)r * 2048 + slot * 64 + tid]
                            : &memI[(size_t)r * 2048 + slot * 64 + (tid - 64)];
      *m = fmaf(wg, gwrL[tid], (1.0f - wg) * (*m));
      // merge token t+1
      int tok = x_seq[r * TT + t + 1];
      gwrL[tid] = fmaf(alpha, gwrL[tid], onema * enc[((size_t)tok << 7) + tid]);
    }
    __syncthreads();
    if (tid < 64) pangG[r * 64 + tid] = atan2f(gwrL[64 + tid], gwrL[tid]);
    if (tid < 128) {
      gwG[r * 128 + tid] = gwrL[tid];
      float lnG = (tid < 64) ? nrg[tid] : nig[tid - 64];
      float lnB = (tid < 64) ? nrb[tid] : nib[tid - 64];
      float val = gwrL[tid];
      float mu = wredsum(val) * 0.015625f;
      float xc = val - mu;
      float vr = wredsum(xc * xc) * 0.015625f;
      zbuf[r * 128 + tid] = xc * (1.0f / sqrtf(vr + 1e-5f)) * lnG + lnB;
    }
  }
}

// ================= decoder =================
__global__ __launch_bounds__(256) void sacrsn_dec(
    const float* __restrict__ dW, const float* __restrict__ dbv,
    float* __restrict__ dout, const char* __restrict__ ws)
{
  const float* outh = (const float*)(ws + OFF_OUTH);
  const float* rst = (const float*)(ws + OFF_RST);
  __shared__ float As[4096];
  __shared__ float Bs[4096];
  const int tid = threadIdx.x;
  const int bx = blockIdx.x & 127;
  const int by = blockIdx.x >> 7;
  const int n0 = bx << 6, m0 = by << 6;
  if (blockIdx.x == 0 && tid < 4) {
    float s = 0.f;
    for (int r = 0; r < 128; ++r) s += rst[r * 4 + tid];
    dout[(size_t)LOGN + tid] = s * (1.0f / 4096.0f);
  }
  const int ty = tid >> 4, tx = tid & 15;
  float acc[4][4];
#pragma unroll
  for (int i = 0; i < 4; ++i)
#pragma unroll
    for (int j = 0; j < 4; ++j) acc[i][j] = 0.f;
  for (int kh = 0; kh < 2; ++kh) {
    for (int u = tid; u < 1024; u += 256) {
      const int row = u >> 4, un = u & 15;
      const int sw = ((un ^ row) & 15) << 2;
      *(float4*)&As[(row << 6) + sw] =
          *(const float4*)&outh[((size_t)(m0 + row) << 7) + (kh << 6) + (un << 2)];
      *(float4*)&Bs[(row << 6) + sw] =
          *(const float4*)&dW[((size_t)(n0 + row) << 7) + (kh << 6) + (un << 2)];
    }
    __syncthreads();
#pragma unroll 4
    for (int k4 = 0; k4 < 16; ++k4) {
      float4 a[4], b[4];
#pragma unroll
      for (int ii = 0; ii < 4; ++ii) {
        const int row = (ty << 2) + ii;
        a[ii] = *(const float4*)&As[(row << 6) + (((k4 ^ row) & 15) << 2)];
      }
#pragma unroll
      for (int jj = 0; jj < 4; ++jj) {
        const int row = (tx << 2) + jj;
        b[jj] = *(const float4*)&Bs[(row << 6) + (((k4 ^ row) & 15) << 2)];
      }
#pragma unroll
      for (int ii = 0; ii < 4; ++ii)
#pragma unroll
        for (int jj = 0; jj < 4; ++jj)
          acc[ii][jj] = fmaf(a[ii].x, b[jj].x, fmaf(a[ii].y, b[jj].y,
                        fmaf(a[ii].z, b[jj].z, fmaf(a[ii].w, b[jj].w, acc[ii][jj]))));
    }
    __syncthreads();
  }
#pragma unroll
  for (int ii = 0; ii < 4; ++ii) {
    const int m = m0 + (ty << 2) + ii;
    const int v0 = n0 + (tx << 2);
    float4 o;
    o.x = acc[ii][0] + dbv[v0];
    o.y = acc[ii][1] + dbv[v0 + 1];
    o.z = acc[ii][2] + dbv[v0 + 2];
    o.w = acc[ii][3] + dbv[v0 + 3];
    *(float4*)&dout[((size_t)m << 13) + v0] = o;
  }
}

extern "C" void kernel_launch(void* const* d_in, const int* in_sizes, int n_in,
                              void* d_out, int out_size, void* d_ws, size_t ws_size,
                              hipStream_t stream) {
  (void)in_sizes; (void)n_in; (void)out_size; (void)ws_size;
  const int*   x_seq = (const int*)d_in[0];
  const float* enc = (const float*)d_in[1];
  const float* vq  = (const float*)d_in[2];
  const float* nrg = (const float*)d_in[3];
  const float* nrb = (const float*)d_in[4];
  const float* nig = (const float*)d_in[5];
  const float* nib = (const float*)d_in[6];
  const float* qWr = (const float*)d_in[7];
  const float* qbr = (const float*)d_in[8];
  const float* qWi = (const float*)d_in[9];
  const float* qbi = (const float*)d_in[10];
  const float* gtw = (const float*)d_in[11];
  const float* gtb = (const float*)d_in[12];
  const float* aW  = (const float*)d_in[13];
  const float* ab  = (const float*)d_in[14];
  const float* dW  = (const float*)d_in[15];
  const float* db  = (const float*)d_in[16];
  const float* hb  = (const float*)d_in[17];
  const float* ig  = (const float*)d_in[18];
  char* ws = (char*)d_ws;
  float* out = (float*)d_out;
  hipLaunchKernelGGL(k_init, dim3(128), dim3(256), 0, stream,
                     x_seq, enc, vq, nrg, nrb, nig, nib, ig, ws);
  for (int t = 0; t < TT; ++t) {
    hipLaunchKernelGGL(k_vq, dim3(256), dim3(256), 0, stream, vq, ws);
    hipLaunchKernelGGL(k_row, dim3(128), dim3(256), 0, stream,
                       x_seq, enc, vq, nrg, nrb, nig, nib, qWr, qbr, qWi, qbi,
                       gtw, gtb, aW, ab, hb, ig, out, ws, t);
  }
  hipLaunchKernelGGL(sacrsn_dec, dim3(8192), dim3(256), 0, stream, dW, db, out, ws);
}

// Round 9
// 817.527 us; speedup vs baseline: 1.4071x; 1.4071x over previous
//
#include <hip/hip_runtime.h>
#include <math.h>

#define TT 32
#define MAXREC 8
#define NBLK 256
#define NTHR 512

// workspace byte offsets
#define OFF_ZBUF   0u          // 128*128 f32 = 65536
#define OFF_KEYS   65536u      // 128*128 u64 = 131072
#define OFF_ZDONE  196608u     // 128 * 16B tagged done-words (owners)
#define OFF_SDONE  198656u     // 128 * 16B tagged done-words (servers)
#define OFF_OUTHB  200704u     // 4096*128 bf16 = 1048576
#define OFF_RST    1249280u    // 128*4 f32 = 2048
#define OFF_DWB    1251328u    // 8192*128 bf16 = 2097152 -> ends 3348480

#define SENT 0x7FFFFFFFu
#define LOGN 33554432u        // 128*32*8192
#define TWO_PI_F 6.283185307179586f

typedef float f32x4 __attribute__((ext_vector_type(4)));
typedef short bf16x8 __attribute__((ext_vector_type(8)));
typedef unsigned long long u64;

__device__ __forceinline__ float wredsum(float v) {
#pragma unroll
  for (int m = 32; m > 0; m >>= 1) v += __shfl_xor(v, m);
  return v;
}

__device__ __forceinline__ u64 shflx64(u64 v, int m) {
  int lo = __shfl_xor((int)(unsigned)(v & 0xffffffffull), m);
  int hi = __shfl_xor((int)(unsigned)(v >> 32), m);
  return ((u64)(unsigned)hi << 32) | (unsigned)lo;
}

__device__ __forceinline__ u64 packkey(float d, unsigned c) {
  unsigned u = __float_as_uint(d);
  u = (u & 0x80000000u) ? ~u : (u | 0x80000000u);
  return ((u64)u << 32) | c;
}
__device__ __forceinline__ float unpackd2(u64 key) {
  unsigned hi = (unsigned)(key >> 32);
  unsigned orig = (hi & 0x80000000u) ? (hi & 0x7fffffffu) : ~hi;
  return __uint_as_float(orig);
}
__device__ __forceinline__ unsigned short f2bf(float f) {
  unsigned u = __float_as_uint(f);
  unsigned r = (u >> 16) & 1u;
  u += 0x7fffu + r;
  return (unsigned short)(u >> 16);
}

// ---- coherent (cross-XCD, L2-bypass) accesses ----
__device__ __forceinline__ unsigned ld_coh32(const unsigned* p) {
  unsigned v;
  asm volatile("global_load_dword %0, %1, off sc0 sc1\n\ts_waitcnt vmcnt(0)"
               : "=&v"(v) : "v"(p) : "memory");
  return v;
}
__device__ __forceinline__ void st_coh_f32(float* p, float v) {
  asm volatile("global_store_dword %0, %1, off sc0 sc1" :: "v"(p), "v"(v) : "memory");
}
__device__ __forceinline__ void st_coh32(unsigned* p, unsigned v) {
  asm volatile("global_store_dword %0, %1, off sc0 sc1" :: "v"(p), "v"(v) : "memory");
}
__device__ __forceinline__ void st_coh64(u64* p, u64 v) {
  asm volatile("global_store_dwordx2 %0, %1, off sc0 sc1" :: "v"(p), "v"(v) : "memory");
}
__device__ __forceinline__ void drain_vm() {
  asm volatile("s_waitcnt vmcnt(0)" ::: "memory");
}

// 8 coherent 16B loads + wait (single round trip)
__device__ __forceinline__ void ld8w(const float* base,
    unsigned o0, unsigned o1, unsigned o2, unsigned o3,
    unsigned o4, unsigned o5, unsigned o6, unsigned o7,
    f32x4& a0, f32x4& a1, f32x4& a2, f32x4& a3,
    f32x4& a4, f32x4& a5, f32x4& a6, f32x4& a7) {
  asm volatile(
      "global_load_dwordx4 %0, %8, %16 sc0 sc1\n\t"
      "global_load_dwordx4 %1, %9, %16 sc0 sc1\n\t"
      "global_load_dwordx4 %2, %10, %16 sc0 sc1\n\t"
      "global_load_dwordx4 %3, %11, %16 sc0 sc1\n\t"
      "global_load_dwordx4 %4, %12, %16 sc0 sc1\n\t"
      "global_load_dwordx4 %5, %13, %16 sc0 sc1\n\t"
      "global_load_dwordx4 %6, %14, %16 sc0 sc1\n\t"
      "global_load_dwordx4 %7, %15, %16 sc0 sc1\n\t"
      "s_waitcnt vmcnt(0)"
      : "=&v"(a0), "=&v"(a1), "=&v"(a2), "=&v"(a3),
        "=&v"(a4), "=&v"(a5), "=&v"(a6), "=&v"(a7)
      : "v"(o0), "v"(o1), "v"(o2), "v"(o3),
        "v"(o4), "v"(o5), "v"(o6), "v"(o7),
        "s"(base)
      : "memory");
}
// 8 coherent 8B loads, no wait (issue only)
__device__ __forceinline__ void ld8x2_issue(const char* base,
    unsigned o0, unsigned o1, unsigned o2, unsigned o3,
    unsigned o4, unsigned o5, unsigned o6, unsigned o7,
    u64& a0, u64& a1, u64& a2, u64& a3, u64& a4, u64& a5, u64& a6, u64& a7) {
  asm volatile(
      "global_load_dwordx2 %0, %8, %16 sc0 sc1\n\t"
      "global_load_dwordx2 %1, %9, %16 sc0 sc1\n\t"
      "global_load_dwordx2 %2, %10, %16 sc0 sc1\n\t"
      "global_load_dwordx2 %3, %11, %16 sc0 sc1\n\t"
      "global_load_dwordx2 %4, %12, %16 sc0 sc1\n\t"
      "global_load_dwordx2 %5, %13, %16 sc0 sc1\n\t"
      "global_load_dwordx2 %6, %14, %16 sc0 sc1\n\t"
      "global_load_dwordx2 %7, %15, %16 sc0 sc1"
      : "=&v"(a0), "=&v"(a1), "=&v"(a2), "=&v"(a3),
        "=&v"(a4), "=&v"(a5), "=&v"(a6), "=&v"(a7)
      : "v"(o0), "v"(o1), "v"(o2), "v"(o3),
        "v"(o4), "v"(o5), "v"(o6), "v"(o7),
        "s"(base)
      : "memory");
}

__global__ __launch_bounds__(512) void sacrsn_init(char* __restrict__ ws) {
  unsigned* zd = (unsigned*)(ws + OFF_ZDONE);
  unsigned* sd = (unsigned*)(ws + OFF_SDONE);
  zd[threadIdx.x] = 0u;
  sd[threadIdx.x] = 0u;
}

// convert dec_W (8192x128 f32) -> bf16
__global__ __launch_bounds__(256) void k_prep(const float* __restrict__ dW,
                                              char* __restrict__ ws) {
  unsigned short* dWb = (unsigned short*)(ws + OFF_DWB);
  const int i = (blockIdx.x * 256 + threadIdx.x) * 4;
  float4 v = *(const float4*)(dW + i);
  ushort4 o;
  o.x = f2bf(v.x); o.y = f2bf(v.y); o.z = f2bf(v.z); o.w = f2bf(v.w);
  *(ushort4*)(dWb + i) = o;
}

__global__ __launch_bounds__(NTHR) void sacrsn_main(
    const int* __restrict__ x_seq, const float* __restrict__ enc,
    const float* __restrict__ vqe,
    const float* __restrict__ nrg, const float* __restrict__ nrb,
    const float* __restrict__ nig, const float* __restrict__ nib,
    const float* __restrict__ qWr, const float* __restrict__ qbr,
    const float* __restrict__ qWi, const float* __restrict__ qbi,
    const float* __restrict__ gtw, const float* __restrict__ gtb,
    const float* __restrict__ aW, const float* __restrict__ ab,
    const float* __restrict__ hbp, const float* __restrict__ igp,
    float* __restrict__ dout, char* __restrict__ ws)
{
  float* zbuf = (float*)(ws + OFF_ZBUF);
  u64*   keys = (u64*)(ws + OFF_KEYS);
  unsigned* zdone = (unsigned*)(ws + OFF_ZDONE);
  unsigned* sdone = (unsigned*)(ws + OFF_SDONE);
  unsigned short* outhB = (unsigned short*)(ws + OFF_OUTHB);
  float* rst  = (float*)(ws + OFF_RST);

  const int tid = threadIdx.x;
  const int wv = tid >> 6, ln = tid & 63;
  const int blk = blockIdx.x;
  const bool owner = (blk < 128);

  __shared__ float els[64 * 128];
  __shared__ float zloc[128 * 128];
  __shared__ u64 vtmp[128 * 17];
  __shared__ float esqL[64];
  __shared__ float z2locL[128];
  __shared__ float memLr[32 * 65];
  __shared__ float memLi[32 * 65];
  __shared__ float gwrowL[128], pangL[64], zfmL[128], zqL[128];
  __shared__ float qkL[6][64], simL[32], attnL[32], mrL[64], miL[64];
  __shared__ unsigned idxL[128] __attribute__((aligned(16)));
  __shared__ u64 key128L[128];
  __shared__ float arbWL[3 * 128];
  __shared__ float scalL[8], entpL[2], vqpL[2], wsumL[2];
  __shared__ float accL[4], totL[4];
  __shared__ float dmeanS;
  __shared__ u64 actM[2], actN[2];
  __shared__ unsigned pollOK, pollSent, mfS;

  const float alpha = 1.0f / (1.0f + expf(-igp[0]));
  const float onema = 1.0f - alpha;
  const float hbias = log1pf(expf(hbp[0]));
  const float gtb0 = gtb[0];

  if (!owner) {
    // ================= VQ server: blocks 128..255, 64 codes each =================
    const int s = blk - 128;
#pragma unroll
    for (int j = 0; j < 4; ++j) {
      int f4 = tid + j * NTHR;
      int c = f4 >> 5, k4 = f4 & 31;
      float4 v = *(const float4*)&vqe[((size_t)(s * 64 + c) << 7) + (k4 << 2)];
      *(float4*)&els[(c << 7) + ((k4 ^ (c & 31)) << 2)] = v;
    }
    __syncthreads();
    if (tid < 64) {
      float sm = 0.0f;
#pragma unroll 8
      for (int k4 = 0; k4 < 32; ++k4) {
        float4 v = *(const float4*)&els[(tid << 7) + ((k4 ^ (tid & 31)) << 2)];
        sm = fmaf(v.x, v.x, fmaf(v.y, v.y, fmaf(v.z, v.z, fmaf(v.w, v.w, sm))));
      }
      esqL[tid] = sm;
    }
    __syncthreads();
    unsigned k = 0;
    while (true) {
      bool done = false;
      while (true) {
        if (tid == 0) { pollOK = 1u; pollSent = 1u; }
        __syncthreads();
        if (tid < 128) {
          unsigned v = ld_coh32(&zdone[tid * 4]);
          if ((int)(v - (k + 1u)) < 0) pollOK = 0u;
          if (v != SENT) pollSent = 0u;
        }
        __syncthreads();
        if (pollSent) { done = true; break; }
        if (pollOK) break;
        __builtin_amdgcn_s_sleep(1);
      }
      if (done) break;
      {
        f32x4 a0, a1, a2, a3, a4, a5, a6, a7;
        const unsigned tb = (unsigned)tid * 16u;
        ld8w(zbuf, tb, tb + 8192u, tb + 16384u, tb + 24576u,
             tb + 32768u, tb + 40960u, tb + 49152u, tb + 57344u,
             a0, a1, a2, a3, a4, a5, a6, a7);
        __builtin_amdgcn_sched_barrier(0);
        f32x4 va[8] = {a0, a1, a2, a3, a4, a5, a6, a7};
#pragma unroll
        for (int u = 0; u < 8; ++u) {
          int f4 = u * NTHR + tid;
          int row = f4 >> 5, k4 = f4 & 31;
          *(f32x4*)&zloc[(row << 7) + ((k4 ^ (row & 31)) << 2)] = va[u];
        }
      }
      __syncthreads();
      if (tid < 128) {
        float sm = 0.0f;
#pragma unroll 8
        for (int k4 = 0; k4 < 32; ++k4) {
          float4 q = *(const float4*)&zloc[(tid << 7) + ((k4 ^ (tid & 31)) << 2)];
          sm = fmaf(q.x, q.x, fmaf(q.y, q.y, fmaf(q.z, q.z, fmaf(q.w, q.w, sm))));
        }
        z2locL[tid] = sm;
      }
      const int rt = tid & 31, ct = tid >> 5;
      float acc[4][4];
#pragma unroll
      for (int rr = 0; rr < 4; ++rr)
#pragma unroll
        for (int cc = 0; cc < 4; ++cc) acc[rr][cc] = 0.0f;
#pragma unroll 2
      for (int k4 = 0; k4 < 32; ++k4) {
        float4 zv[4], ev[4];
#pragma unroll
        for (int rr = 0; rr < 4; ++rr)
          zv[rr] = *(const float4*)&zloc[((rt + rr * 32) << 7) + ((k4 ^ rt) << 2)];
#pragma unroll
        for (int cc = 0; cc < 4; ++cc) {
          int cl = ct * 4 + cc;
          ev[cc] = *(const float4*)&els[(cl << 7) + ((k4 ^ (cl & 31)) << 2)];
        }
#pragma unroll
        for (int rr = 0; rr < 4; ++rr)
#pragma unroll
          for (int cc = 0; cc < 4; ++cc)
            acc[rr][cc] = fmaf(zv[rr].x, ev[cc].x, fmaf(zv[rr].y, ev[cc].y,
                          fmaf(zv[rr].z, ev[cc].z, fmaf(zv[rr].w, ev[cc].w, acc[rr][cc]))));
      }
      __syncthreads();
#pragma unroll
      for (int rr = 0; rr < 4; ++rr) {
        const int row = rt + rr * 32;
        const float z2r = z2locL[row];
        u64 key = ~0ull;
#pragma unroll
        for (int cc = 0; cc < 4; ++cc) {
          int cl = ct * 4 + cc;
          float d2 = (z2r - 2.0f * acc[rr][cc]) + esqL[cl];
          u64 pk = packkey(d2, (unsigned)(s * 64 + cl));
          if (pk < key) key = pk;
        }
        vtmp[row * 17 + ct] = key;
      }
      __syncthreads();
      if (tid < 128) {
        u64 kmin = vtmp[tid * 17];
#pragma unroll
        for (int w = 1; w < 16; ++w) { u64 o = vtmp[tid * 17 + w]; if (o < kmin) kmin = o; }
        st_coh64(&keys[(size_t)s * 128 + tid], kmin);
      }
      drain_vm();
      __syncthreads();
      if (tid == 0) st_coh32(&sdone[s * 4], k + 1u);
      k++;
    }
    return;
  }

  // ================= owner: blocks 0..127, row = blk =================
  float lnG = 0.0f, lnB = 0.0f, gtwv = 0.0f;
  if (tid < 64) { lnG = nrg[tid]; lnB = nrb[tid]; }
  else if (tid < 128) { lnG = nig[tid - 64]; lnB = nib[tid - 64]; }
  if (tid < 128) gtwv = gtw[tid];
  for (int i = tid; i < 32 * 65; i += NTHR) { memLr[i] = 0.0f; memLi[i] = 0.0f; }
  if (tid < 4) { totL[tid] = 0.0f; accL[tid] = 0.0f; }
  if (tid < 2) actM[tid] = ~0ull;
  for (int i = tid; i < 384; i += NTHR) arbWL[i] = aW[i];
  {
    int tok = x_seq[blk * TT];
    if (tid < 128) gwrowL[tid] = onema * enc[((size_t)tok << 7) + tid];
  }
  __syncthreads();
  if (tid < 64) pangL[tid] = atan2f(gwrowL[64 + tid], gwrowL[tid]);
  if (tid < 128) {
    float val = gwrowL[tid];
    float mu = wredsum(val) * 0.015625f;
    float xc = val - mu;
    float vr = wredsum(xc * xc) * 0.015625f;
    float z = xc * (1.0f / sqrtf(vr + 1e-5f)) * lnG + lnB;
    zfmL[tid] = z;
    st_coh_f32(&zbuf[(blk << 7) + tid], z);
  }
  drain_vm();
  __syncthreads();
  if (tid == 0) st_coh32(&zdone[blk * 4], 1u);

  int t = 0, it = 0;
  unsigned k = 0;
  for (;;) {
    float encN = 0.0f;
    {
      int tnext = (t + 1 < TT) ? t + 1 : t;
      if (tid < 128) {
        int tk = x_seq[blk * TT + tnext];
        encN = enc[((size_t)tk << 7) + tid];
      }
    }
    if (tid < 192) {
      const int h = tid >> 6, j = tid & 63;
      const float* wr = qWr + h * 4096 + j * 64;
      const float* wi = qWi + h * 4096 + j * 64;
      float da = 0.0f, db_ = 0.0f, dc = 0.0f, de = 0.0f;
#pragma unroll 4
      for (int d4 = 0; d4 < 64; d4 += 4) {
        float4 wrv = *(const float4*)&wr[d4];
        float4 wiv = *(const float4*)&wi[d4];
        float4 crv = *(const float4*)&zfmL[d4];
        float4 civ = *(const float4*)&zfmL[64 + d4];
        da = fmaf(crv.x, wrv.x, fmaf(crv.y, wrv.y, fmaf(crv.z, wrv.z, fmaf(crv.w, wrv.w, da))));
        db_ = fmaf(civ.x, wiv.x, fmaf(civ.y, wiv.y, fmaf(civ.z, wiv.z, fmaf(civ.w, wiv.w, db_))));
        dc = fmaf(civ.x, wrv.x, fmaf(civ.y, wrv.y, fmaf(civ.z, wrv.z, fmaf(civ.w, wrv.w, dc))));
        de = fmaf(crv.x, wiv.x, fmaf(crv.y, wiv.y, fmaf(crv.z, wiv.z, fmaf(crv.w, wiv.w, de))));
      }
      float brv = qbr[h * 64 + j], biv = qbi[h * 64 + j];
      qkL[2 * h][j] = da + brv - db_ - biv;
      qkL[2 * h + 1][j] = dc + brv + de + biv;
    } else if (tid < 224) {
      const int s2 = tid - 192;
      float a2 = 0.0f;
      for (int d = 0; d < 64; ++d)
        a2 = fmaf(memLr[s2 * 65 + d], zfmL[d], fmaf(memLi[s2 * 65 + d], zfmL[64 + d], a2));
      simL[s2] = a2;
    } else if (tid < 227) {
      const int h = tid - 224;
      float a2 = ab[h];
      for (int k2 = 0; k2 < 128; ++k2) a2 = fmaf(zfmL[k2], arbWL[h * 128 + k2], a2);
      scalL[3 + h] = a2;
    }
    __syncthreads();
    if (tid < 64) {
      float p = fmaf(qkL[0][tid], qkL[2][tid], qkL[1][tid] * qkL[3][tid]);
      p = wredsum(p);
      if (tid == 0) scalL[0] = 1.0f / (1.0f + expf(-p));
    } else if (tid < 96) {
      const int s2 = tid - 64;
      float v = simL[s2];
      float m = v;
#pragma unroll
      for (int msk = 16; msk > 0; msk >>= 1) m = fmaxf(m, __shfl_xor(m, msk));
      float e = expf(v - m);
      float ss = e;
#pragma unroll
      for (int msk = 16; msk > 0; msk >>= 1) ss += __shfl_xor(ss, msk);
      attnL[s2] = e / ss;
    } else if (tid == 96) {
      float a0 = scalL[3], a1 = scalL[4], a2 = scalL[5];
      float m = fmaxf(a0, fmaxf(a1, a2));
      float e0 = expf(a0 - m), e1 = expf(a1 - m), e2 = expf(a2 - m);
      float ssum = e0 + e1 + e2;
      scalL[3] = e0 / ssum; scalL[4] = e1 / ssum; scalL[5] = e2 / ssum;
    }
    __syncthreads();
    if (tid < 128) {
      const int d = ln;
      const float* ml = (wv == 0) ? memLr : memLi;
      float a2 = 0.0f;
#pragma unroll 4
      for (int s2 = 0; s2 < 32; ++s2) a2 = fmaf(attnL[s2], ml[s2 * 65 + d], a2);
      if (wv == 0) mrL[d] = a2; else miL[d] = a2;
    }
    while (true) {
      if (tid == 0) pollOK = 1u;
      __syncthreads();
      if (tid < 128) {
        unsigned v = ld_coh32(&sdone[tid * 4]);
        if ((int)(v - (k + 1u)) < 0) pollOK = 0u;
      }
      __syncthreads();
      if (pollOK) break;
      __builtin_amdgcn_s_sleep(1);
    }
    {
      const int r = tid >> 2, sc = tid & 3;
      const char* kb = (const char*)keys;
      const unsigned bo = (unsigned)(sc * 32768 + r * 8);
      u64 g00, g01, g02, g03, g04, g05, g06, g07;
      u64 g10, g11, g12, g13, g14, g15, g16, g17;
      u64 g20, g21, g22, g23, g24, g25, g26, g27;
      u64 g30, g31, g32, g33, g34, g35, g36, g37;
      ld8x2_issue(kb, bo, bo + 1024u, bo + 2048u, bo + 3072u,
                  bo + 4096u, bo + 5120u, bo + 6144u, bo + 7168u,
                  g00, g01, g02, g03, g04, g05, g06, g07);
      ld8x2_issue(kb, bo + 8192u, bo + 9216u, bo + 10240u, bo + 11264u,
                  bo + 12288u, bo + 13312u, bo + 14336u, bo + 15360u,
                  g10, g11, g12, g13, g14, g15, g16, g17);
      ld8x2_issue(kb, bo + 16384u, bo + 17408u, bo + 18432u, bo + 19456u,
                  bo + 20480u, bo + 21504u, bo + 22528u, bo + 23552u,
                  g20, g21, g22, g23, g24, g25, g26, g27);
      ld8x2_issue(kb, bo + 24576u, bo + 25600u, bo + 26624u, bo + 27648u,
                  bo + 28672u, bo + 29696u, bo + 30720u, bo + 31744u,
                  g30, g31, g32, g33, g34, g35, g36, g37);
      drain_vm();
      __builtin_amdgcn_sched_barrier(0);
      u64 m = g00;
      if (g01 < m) m = g01; if (g02 < m) m = g02; if (g03 < m) m = g03;
      if (g04 < m) m = g04; if (g05 < m) m = g05; if (g06 < m) m = g06; if (g07 < m) m = g07;
      if (g10 < m) m = g10; if (g11 < m) m = g11; if (g12 < m) m = g12; if (g13 < m) m = g13;
      if (g14 < m) m = g14; if (g15 < m) m = g15; if (g16 < m) m = g16; if (g17 < m) m = g17;
      if (g20 < m) m = g20; if (g21 < m) m = g21; if (g22 < m) m = g22; if (g23 < m) m = g23;
      if (g24 < m) m = g24; if (g25 < m) m = g25; if (g26 < m) m = g26; if (g27 < m) m = g27;
      if (g30 < m) m = g30; if (g31 < m) m = g31; if (g32 < m) m = g32; if (g33 < m) m = g33;
      if (g34 < m) m = g34; if (g35 < m) m = g35; if (g36 < m) m = g36; if (g37 < m) m = g37;
      u64 o = shflx64(m, 1); if (o < m) m = o;
      o = shflx64(m, 2); if (o < m) m = o;
      if (sc == 0) key128L[r] = m;
    }
    __syncthreads();
    if (tid < 128) {
      u64 key = key128L[tid];
      idxL[tid] = (unsigned)key;
      float d2 = unpackd2(key);
      bool act_b = ((actM[tid >> 6] >> (tid & 63)) & 1ull) != 0ull;
      bool stop = (1.25f * 0.0078125f * d2) < hbias;
      u64 ball = __ballot(act_b && !stop);
      if (ln == 0) actN[tid >> 6] = ball;
    }
    __syncthreads();
    if (tid == 0) mfS = (unsigned)((actM[blk >> 6] >> (blk & 63)) & 1ull);
    if (tid < 2) actM[tid] = actN[tid];
    __syncthreads();
    const bool anyAct = (actN[0] | actN[1]) != 0ull;
    const bool mf = mfS != 0u;
    const unsigned ii = idxL[blk];
    if (tid < 128) {
      float zq = vqe[((size_t)ii << 7) + tid];
      zqL[tid] = zq;
      float df = zq - zfmL[tid];
      float sm = wredsum(df * df);
      if (ln == 0) vqpL[wv] = sm;
    } else if (tid < 256) {
      const int r = tid - 128;
      unsigned my = idxL[r];
      int c = 0;
#pragma unroll
      for (int j4 = 0; j4 < 32; ++j4) {
        uint4 q = *(const uint4*)&idxL[j4 * 4];
        c += (q.x == my) + (q.y == my) + (q.z == my) + (q.w == my);
      }
      float term = -0.0078125f * logf((float)c * 0.0078125f + 1e-10f);
      term = wredsum(term);
      if (ln == 0) entpL[wv - 2] = term;
    }
    __syncthreads();
    if (tid < 64) {
      const int d = tid;
      float gate = scalL[0], g0 = scalL[3], g1 = scalL[4], g2 = scalL[5];
      float cr = zfmL[d], ci = zfmL[64 + d];
      float ur = fmaf(g0, qkL[4][d] * gate, fmaf(g1, mrL[d], g2 * zqL[d]));
      float ui = fmaf(g0, qkL[5][d] * gate, fmaf(g1, miL[d], g2 * zqL[64 + d]));
      float cdr = fmaf(0.4f, ur, 0.6f * cr);
      float cdi = fmaf(0.4f, ui, 0.6f * ci);
      float ang = atan2f(cdi, cdr);
      float df = fabsf(ang - pangL[d]);
      df = fminf(df, TWO_PI_F - df);
      pangL[d] = ang;
      float dm = wredsum(df) * 0.015625f;
      if (mf) { gwrowL[d] = cdr; gwrowL[64 + d] = cdi; }
      if (d == 0) dmeanS = dm;
    }
    __syncthreads();
    const bool newT = !(anyAct && it < MAXREC - 1);
    const bool finished = newT && (t == TT - 1);
    if (newT && !finished) {
      float pr = 0.0f;
      if (tid < 128) {
        pr = gwrowL[tid];
        outhB[((size_t)blk * TT + t) * 128 + tid] = f2bf(pr);
        float part = wredsum(pr * gtwv);
        if (ln == 0) wsumL[wv] = part;
      }
      __syncthreads();
      if (tid < 128) {
        float wg = 1.0f / (1.0f + expf(-(wsumL[0] + wsumL[1] + gtb0)));
        int slot = 31 - t;
        float* m = (tid < 64) ? &memLr[slot * 65 + tid] : &memLi[slot * 65 + (tid - 64)];
        *m = fmaf(wg, pr, (1.0f - wg) * (*m));
        gwrowL[tid] = fmaf(alpha, pr, onema * encN);
      }
      __syncthreads();
    }
    if (!finished) {
      if (tid < 128) {
        float val = gwrowL[tid];
        float mu = wredsum(val) * 0.015625f;
        float xc = val - mu;
        float vr = wredsum(xc * xc) * 0.015625f;
        float z = xc * (1.0f / sqrtf(vr + 1e-5f)) * lnG + lnB;
        zfmL[tid] = z;
        st_coh_f32(&zbuf[(blk << 7) + tid], z);
      }
      drain_vm();
      __syncthreads();
      if (tid == 0) st_coh32(&zdone[blk * 4], k + 2u);
    } else {
      __syncthreads();
    }
    if (tid == 0) {
      float aold = mf ? 1.0f : 0.0f;
      float vql = 1.25f * (vqpL[0] + vqpL[1]) * 0.0078125f;
      accL[3] += aold * dmeanS;
      accL[2] += aold * 0.01f;
      if (mf) {
        accL[0] = vql;
        accL[1] = entpL[0] + entpL[1];
        dout[(size_t)LOGN + 4 + (size_t)blk * TT + t] = (float)ii;
      }
    }
    if (newT && !finished) {
      if (tid < 64) pangL[tid] = atan2f(gwrowL[64 + tid], gwrowL[tid]);
      if (tid < 4) { totL[tid] += accL[tid]; accL[tid] = 0.0f; }
      if (tid < 2) actM[tid] = ~0ull;
    }
    __syncthreads();
    if (finished) break;
    if (newT) { t++; it = 0; } else { it++; }
    k++;
  }

  // epilogue
  if (tid < 128) outhB[((size_t)blk * TT + (TT - 1)) * 128 + tid] = f2bf(gwrowL[tid]);
  if (tid < 4) rst[blk * 4 + tid] = totL[tid] + accL[tid];
  __syncthreads();
  if (tid == 0) st_coh32(&zdone[blk * 4], SENT);
}

// ================= MFMA decoder: 4096x8192x128 bf16 -> f32 =================
__global__ __launch_bounds__(256) void k_dec(
    const float* __restrict__ dbv, float* __restrict__ dout,
    const char* __restrict__ ws)
{
  const unsigned short* outhB = (const unsigned short*)(ws + OFF_OUTHB);
  const unsigned short* dWb = (const unsigned short*)(ws + OFF_DWB);
  const float* rst = (const float*)(ws + OFF_RST);
  const int tid = threadIdx.x;
  if (blockIdx.x == 0 && tid < 4) {   // deterministic stats reduction
    float s = 0.0f;
    for (int r = 0; r < 128; ++r) s += rst[r * 4 + tid];
    dout[(size_t)LOGN + tid] = s * (1.0f / 4096.0f);
  }
  const int w = tid >> 6, l = tid & 63;
  const int bm = blockIdx.x & 63;       // 64 m-blocks of 64 rows
  const int bn = blockIdx.x >> 6;       // 32 n-blocks of 256 cols
  const int ar = l & 15, kg = l >> 4;
  const int m_base = bm * 64;
  const int n_base = bn * 256 + w * 64;
  f32x4 acc[4][4];
#pragma unroll
  for (int mt = 0; mt < 4; ++mt)
#pragma unroll
    for (int nt = 0; nt < 4; ++nt) acc[mt][nt] = (f32x4){0.f, 0.f, 0.f, 0.f};
#pragma unroll
  for (int kc = 0; kc < 4; ++kc) {
    const int ko = kc * 32 + kg * 8;
    bf16x8 a[4], b[4];
#pragma unroll
    for (int mt = 0; mt < 4; ++mt)
      a[mt] = *(const bf16x8*)(outhB + (size_t)(m_base + mt * 16 + ar) * 128 + ko);
#pragma unroll
    for (int nt = 0; nt < 4; ++nt)
      b[nt] = *(const bf16x8*)(dWb + (size_t)(n_base + nt * 16 + ar) * 128 + ko);
#pragma unroll
    for (int mt = 0; mt < 4; ++mt)
#pragma unroll
      for (int nt = 0; nt < 4; ++nt)
        acc[mt][nt] = __builtin_amdgcn_mfma_f32_16x16x32_bf16(a[mt], b[nt], acc[mt][nt], 0, 0, 0);
  }
#pragma unroll
  for (int nt = 0; nt < 4; ++nt) {
    const int n = n_base + nt * 16 + ar;
    const float bv = dbv[n];
#pragma unroll
    for (int mt = 0; mt < 4; ++mt) {
#pragma unroll
      for (int rr = 0; rr < 4; ++rr) {
        const int m = m_base + mt * 16 + kg * 4 + rr;
        dout[(size_t)m * 8192 + n] = acc[mt][nt][rr] + bv;
      }
    }
  }
}

extern "C" void kernel_launch(void* const* d_in, const int* in_sizes, int n_in,
                              void* d_out, int out_size, void* d_ws, size_t ws_size,
                              hipStream_t stream) {
  (void)in_sizes; (void)n_in; (void)out_size; (void)ws_size;
  const int*   x_seq = (const int*)d_in[0];
  const float* enc = (const float*)d_in[1];
  const float* vq  = (const float*)d_in[2];
  const float* nrg = (const float*)d_in[3];
  const float* nrb = (const float*)d_in[4];
  const float* nig = (const float*)d_in[5];
  const float* nib = (const float*)d_in[6];
  const float* qWr = (const float*)d_in[7];
  const float* qbr = (const float*)d_in[8];
  const float* qWi = (const float*)d_in[9];
  const float* qbi = (const float*)d_in[10];
  const float* gtw = (const float*)d_in[11];
  const float* gtb = (const float*)d_in[12];
  const float* aW  = (const float*)d_in[13];
  const float* ab  = (const float*)d_in[14];
  const float* dW  = (const float*)d_in[15];
  const float* db  = (const float*)d_in[16];
  const float* hb  = (const float*)d_in[17];
  const float* ig  = (const float*)d_in[18];
  char* ws = (char*)d_ws;
  float* out = (float*)d_out;
  hipLaunchKernelGGL(sacrsn_init, dim3(1), dim3(512), 0, stream, ws);
  hipLaunchKernelGGL(k_prep, dim3(1024), dim3(256), 0, stream, dW, ws);
  hipLaunchKernelGGL(sacrsn_main, dim3(NBLK), dim3(NTHR), 0, stream,
                     x_seq, enc, vq, nrg, nrb, nig, nib, qWr, qbr, qWi, qbi,
                     gtw, gtb, aW, ab, hb, ig, out, ws);
  hipLaunchKernelGGL(k_dec, dim3(2048), dim3(256), 0, stream, db, out, ws);
}

// Round 10
// 738.765 us; speedup vs baseline: 1.5571x; 1.1066x over previous
//
#include <hip/hip_runtime.h>
#include <math.h>

#define TT 32
#define MAXREC 8
#define NBLK 256
#define NTHR 1024

// workspace byte offsets
#define OFF_ZBUF   0u          // 128*128 f32 = 65536
#define OFF_KEYS   65536u      // 128 servers * 128 rows * 8B = 131072 (tag-embedded)
#define OFF_ZDONE  196608u     // 128 * 16B tagged done-words (owners)
#define OFF_FINAL  198656u     // 128 u64 tagged per-row final keys
#define OFF_OUTHB  200704u     // 4096*128 bf16 = 1048576
#define OFF_RST    1249280u    // 128*4 f32 = 2048
#define OFF_DWB    1251328u    // 8192*128 bf16 = 2097152 -> ends 3348480

#define SENT 0x7FFFFFFFu
#define IDXM 0x1FFFu
#define LOGN 33554432u        // 128*32*8192
#define TWO_PI_F 6.283185307179586f

typedef float f32x4 __attribute__((ext_vector_type(4)));
typedef short bf16x8 __attribute__((ext_vector_type(8)));
typedef unsigned long long u64;

__device__ __forceinline__ float wredsum(float v) {
#pragma unroll
  for (int m = 32; m > 0; m >>= 1) v += __shfl_xor(v, m);
  return v;
}

__device__ __forceinline__ u64 shflx64(u64 v, int m) {
  int lo = __shfl_xor((int)(unsigned)(v & 0xffffffffull), m);
  int hi = __shfl_xor((int)(unsigned)(v >> 32), m);
  return ((u64)(unsigned)hi << 32) | (unsigned)lo;
}

// monotone float->u32, pack with 13-bit idx: u64-min == (min dist, then min idx)
__device__ __forceinline__ u64 packkey(float d, unsigned c) {
  unsigned u = __float_as_uint(d);
  u = (u & 0x80000000u) ? ~u : (u | 0x80000000u);
  return ((u64)u << 32) | c;
}
__device__ __forceinline__ float unpackd2(u64 key) {
  unsigned hi = (unsigned)(key >> 32);
  unsigned orig = (hi & 0x80000000u) ? (hi & 0x7fffffffu) : ~hi;
  return __uint_as_float(orig);
}
__device__ __forceinline__ unsigned short f2bf(float f) {
  unsigned u = __float_as_uint(f);
  unsigned r = (u >> 16) & 1u;
  u += 0x7fffu + r;
  return (unsigned short)(u >> 16);
}

// ---- coherent (cross-XCD, L2-bypass) accesses ----
__device__ __forceinline__ unsigned ld_coh32(const unsigned* p) {
  unsigned v;
  asm volatile("global_load_dword %0, %1, off sc0 sc1\n\ts_waitcnt vmcnt(0)"
               : "=&v"(v) : "v"(p) : "memory");
  return v;
}
__device__ __forceinline__ u64 ld_coh64(const u64* p) {
  u64 v;
  asm volatile("global_load_dwordx2 %0, %1, off sc0 sc1\n\ts_waitcnt vmcnt(0)"
               : "=&v"(v) : "v"(p) : "memory");
  return v;
}
__device__ __forceinline__ void st_coh_f32(float* p, float v) {
  asm volatile("global_store_dword %0, %1, off sc0 sc1" :: "v"(p), "v"(v) : "memory");
}
__device__ __forceinline__ void st_coh32(unsigned* p, unsigned v) {
  asm volatile("global_store_dword %0, %1, off sc0 sc1" :: "v"(p), "v"(v) : "memory");
}
__device__ __forceinline__ void st_coh64(u64* p, u64 v) {
  asm volatile("global_store_dwordx2 %0, %1, off sc0 sc1" :: "v"(p), "v"(v) : "memory");
}
__device__ __forceinline__ void drain_vm() {
  asm volatile("s_waitcnt vmcnt(0)" ::: "memory");
}

// 4 coherent 16B loads + wait (single round trip)
__device__ __forceinline__ void ld4w(const float* base,
    unsigned o0, unsigned o1, unsigned o2, unsigned o3,
    f32x4& a0, f32x4& a1, f32x4& a2, f32x4& a3) {
  asm volatile(
      "global_load_dwordx4 %0, %4, %8 sc0 sc1\n\t"
      "global_load_dwordx4 %1, %5, %8 sc0 sc1\n\t"
      "global_load_dwordx4 %2, %6, %8 sc0 sc1\n\t"
      "global_load_dwordx4 %3, %7, %8 sc0 sc1\n\t"
      "s_waitcnt vmcnt(0)"
      : "=&v"(a0), "=&v"(a1), "=&v"(a2), "=&v"(a3)
      : "v"(o0), "v"(o1), "v"(o2), "v"(o3), "s"(base)
      : "memory");
}

__global__ __launch_bounds__(512) void sacrsn_init(char* __restrict__ ws) {
  unsigned* zd = (unsigned*)(ws + OFF_ZDONE);
  u64* fin = (u64*)(ws + OFF_FINAL);
  zd[threadIdx.x] = 0u;
  if (threadIdx.x < 128) fin[threadIdx.x] = 0ull;
}

// convert dec_W (8192x128 f32) -> bf16
__global__ __launch_bounds__(256) void k_prep(const float* __restrict__ dW,
                                              char* __restrict__ ws) {
  unsigned short* dWb = (unsigned short*)(ws + OFF_DWB);
  const int i = (blockIdx.x * 256 + threadIdx.x) * 4;
  float4 v = *(const float4*)(dW + i);
  ushort4 o;
  o.x = f2bf(v.x); o.y = f2bf(v.y); o.z = f2bf(v.z); o.w = f2bf(v.w);
  *(ushort4*)(dWb + i) = o;
}

__global__ __launch_bounds__(NTHR) void sacrsn_main(
    const int* __restrict__ x_seq, const float* __restrict__ enc,
    const float* __restrict__ vqe,
    const float* __restrict__ nrg, const float* __restrict__ nrb,
    const float* __restrict__ nig, const float* __restrict__ nib,
    const float* __restrict__ qWr, const float* __restrict__ qbr,
    const float* __restrict__ qWi, const float* __restrict__ qbi,
    const float* __restrict__ gtw, const float* __restrict__ gtb,
    const float* __restrict__ aW, const float* __restrict__ ab,
    const float* __restrict__ hbp, const float* __restrict__ igp,
    float* __restrict__ dout, char* __restrict__ ws)
{
  float* zbuf = (float*)(ws + OFF_ZBUF);
  u64*   keys = (u64*)(ws + OFF_KEYS);
  unsigned* zdone = (unsigned*)(ws + OFF_ZDONE);
  u64*   finalA = (u64*)(ws + OFF_FINAL);
  unsigned short* outhB = (unsigned short*)(ws + OFF_OUTHB);
  float* rst  = (float*)(ws + OFF_RST);

  const int tid = threadIdx.x;
  const int wv = tid >> 6, ln = tid & 63;
  const int blk = blockIdx.x;
  const bool owner = (blk < 128);

  __shared__ float els[64 * 128];         // 32 KB
  __shared__ float zloc[128 * 128];       // 64 KB
  __shared__ u64 vtmp[128 * 17];          // 17 KB
  __shared__ float esqL[64];
  __shared__ float z2locL[128];
  __shared__ float memLr[32 * 65];
  __shared__ float memLi[32 * 65];
  __shared__ float gwrowL[128], pangL[64], zfmL[128], zqL[128];
  __shared__ float qkL[6][64], simL[32], attnL[32], mrL[64], miL[64];
  __shared__ unsigned idxL[128] __attribute__((aligned(16)));
  __shared__ u64 key128L[128], kred[128];
  __shared__ float arbWL[3 * 128];
  __shared__ float scalL[8], entpL[2], vqpL[2], wsumL[2];
  __shared__ float accL[4], totL[4];
  __shared__ float dmeanS;
  __shared__ u64 actM[2], actN[2];
  __shared__ unsigned pollOK, pollSent, mfS;

  const float alpha = 1.0f / (1.0f + expf(-igp[0]));
  const float onema = 1.0f - alpha;
  const float hbias = log1pf(expf(hbp[0]));
  const float gtb0 = gtb[0];

  if (!owner) {
    // ================= VQ server: blocks 128..255, 64 codes each =================
    const int s = blk - 128;
#pragma unroll
    for (int j = 0; j < 2; ++j) {
      int f4 = tid + j * NTHR;           // 0..2047
      int c = f4 >> 5, k4 = f4 & 31;
      float4 v = *(const float4*)&vqe[((size_t)(s * 64 + c) << 7) + (k4 << 2)];
      *(float4*)&els[(c << 7) + ((k4 ^ (c & 31)) << 2)] = v;
    }
    __syncthreads();
    if (tid < 64) {
      float sm = 0.0f;
#pragma unroll 8
      for (int k4 = 0; k4 < 32; ++k4) {
        float4 v = *(const float4*)&els[(tid << 7) + ((k4 ^ (tid & 31)) << 2)];
        sm = fmaf(v.x, v.x, fmaf(v.y, v.y, fmaf(v.z, v.z, fmaf(v.w, v.w, sm))));
      }
      esqL[tid] = sm;
    }
    __syncthreads();
    unsigned k = 0;
    while (true) {
      bool done = false;
      while (true) {
        if (tid == 0) { pollOK = 1u; pollSent = 1u; }
        __syncthreads();
        if (tid < 128) {
          unsigned v = ld_coh32(&zdone[tid * 4]);
          if ((int)(v - (k + 1u)) < 0) pollOK = 0u;
          if (v != SENT) pollSent = 0u;
        }
        __syncthreads();
        if (pollSent) { done = true; break; }
        if (pollOK) break;
        __builtin_amdgcn_s_sleep(1);
      }
      if (done) break;
      // stage z (single RT, 4 atoms/thread)
      {
        f32x4 a0, a1, a2, a3;
        const unsigned tb = (unsigned)tid * 16u;
        ld4w(zbuf, tb, tb + 16384u, tb + 32768u, tb + 49152u, a0, a1, a2, a3);
        __builtin_amdgcn_sched_barrier(0);
        f32x4 va[4] = {a0, a1, a2, a3};
#pragma unroll
        for (int u = 0; u < 4; ++u) {
          int f4 = u * NTHR + tid;
          int row = f4 >> 5, k4 = f4 & 31;
          *(f32x4*)&zloc[(row << 7) + ((k4 ^ (row & 31)) << 2)] = va[u];
        }
      }
      __syncthreads();
      if (tid < 128) {
        float sm = 0.0f;
#pragma unroll 8
        for (int k4 = 0; k4 < 32; ++k4) {
          float4 q = *(const float4*)&zloc[(tid << 7) + ((k4 ^ (tid & 31)) << 2)];
          sm = fmaf(q.x, q.x, fmaf(q.y, q.y, fmaf(q.z, q.z, fmaf(q.w, q.w, sm))));
        }
        z2locL[tid] = sm;
      }
      // VQ: 2 rows x 4 codes per thread (1024 threads)
      const int rt = tid & 63, ct = tid >> 6;   // ct 0..15
      float acc[2][4];
#pragma unroll
      for (int rr = 0; rr < 2; ++rr)
#pragma unroll
        for (int cc = 0; cc < 4; ++cc) acc[rr][cc] = 0.0f;
#pragma unroll 2
      for (int k4 = 0; k4 < 32; ++k4) {
        float4 zv[2], ev[4];
#pragma unroll
        for (int rr = 0; rr < 2; ++rr)
          zv[rr] = *(const float4*)&zloc[((rt + rr * 64) << 7) + ((k4 ^ (rt & 31)) << 2)];
#pragma unroll
        for (int cc = 0; cc < 4; ++cc) {
          int cl = ct * 4 + cc;
          ev[cc] = *(const float4*)&els[(cl << 7) + ((k4 ^ (cl & 31)) << 2)];
        }
#pragma unroll
        for (int rr = 0; rr < 2; ++rr)
#pragma unroll
          for (int cc = 0; cc < 4; ++cc)
            acc[rr][cc] = fmaf(zv[rr].x, ev[cc].x, fmaf(zv[rr].y, ev[cc].y,
                          fmaf(zv[rr].z, ev[cc].z, fmaf(zv[rr].w, ev[cc].w, acc[rr][cc]))));
      }
      __syncthreads();
#pragma unroll
      for (int rr = 0; rr < 2; ++rr) {
        const int row = rt + rr * 64;
        const float z2r = z2locL[row];
        u64 key = ~0ull;
#pragma unroll
        for (int cc = 0; cc < 4; ++cc) {
          int cl = ct * 4 + cc;
          float d2 = (z2r - 2.0f * acc[rr][cc]) + esqL[cl];
          u64 pk = packkey(d2, (unsigned)(s * 64 + cl));
          if (pk < key) key = pk;
        }
        vtmp[row * 17 + ct] = key;
      }
      __syncthreads();
      if (tid < 128) {
        u64 kmin = vtmp[tid * 17];
#pragma unroll
        for (int w = 1; w < 16; ++w) { u64 o = vtmp[tid * 17 + w]; if (o < kmin) kmin = o; }
        // embed tag in bits 13..31 (8B store atomic => tag-fresh implies data-fresh)
        st_coh64(&keys[(size_t)s * 128 + tid], kmin | ((u64)(k + 1u) << 13));
      }
      k++;
    }
    return;
  }

  // ================= owner: blocks 0..127, row = blk =================
  float lnG = 0.0f, lnB = 0.0f, gtwv = 0.0f;
  if (tid < 64) { lnG = nrg[tid]; lnB = nrb[tid]; }
  else if (tid < 128) { lnG = nig[tid - 64]; lnB = nib[tid - 64]; }
  if (tid < 128) gtwv = gtw[tid];
  for (int i = tid; i < 32 * 65; i += NTHR) { memLr[i] = 0.0f; memLi[i] = 0.0f; }
  if (tid < 4) { totL[tid] = 0.0f; accL[tid] = 0.0f; }
  if (tid < 2) actM[tid] = ~0ull;
  for (int i = tid; i < 384; i += NTHR) arbWL[i] = aW[i];
  {
    int tok = x_seq[blk * TT];
    if (tid < 128) gwrowL[tid] = onema * enc[((size_t)tok << 7) + tid];
  }
  __syncthreads();
  if (tid < 64) pangL[tid] = atan2f(gwrowL[64 + tid], gwrowL[tid]);
  if (tid < 128) {
    float val = gwrowL[tid];
    float mu = wredsum(val) * 0.015625f;
    float xc = val - mu;
    float vr = wredsum(xc * xc) * 0.015625f;
    float z = xc * (1.0f / sqrtf(vr + 1e-5f)) * lnG + lnB;
    zfmL[tid] = z;
    st_coh_f32(&zbuf[(blk << 7) + tid], z);
  }
  drain_vm();
  __syncthreads();
  if (tid == 0) st_coh32(&zdone[blk * 4], 1u);

  int t = 0, it = 0;
  unsigned k = 0;
  for (;;) {
    const unsigned tag = k + 1u;
    float encN = 0.0f;
    {
      int tnext = (t + 1 < TT) ? t + 1 : t;
      if (tid < 128) {
        int tk = x_seq[blk * TT + tnext];
        encN = enc[((size_t)tk << 7) + tid];
      }
    }
    // ---------- C-prep on zfmL (overlaps server VQ) ----------
    if (tid < 192) {
      const int h = tid >> 6, j = tid & 63;
      const float* wr = qWr + h * 4096 + j * 64;
      const float* wi = qWi + h * 4096 + j * 64;
      float da = 0.0f, db_ = 0.0f, dc = 0.0f, de = 0.0f;
#pragma unroll 4
      for (int d4 = 0; d4 < 64; d4 += 4) {
        float4 wrv = *(const float4*)&wr[d4];
        float4 wiv = *(const float4*)&wi[d4];
        float4 crv = *(const float4*)&zfmL[d4];
        float4 civ = *(const float4*)&zfmL[64 + d4];
        da = fmaf(crv.x, wrv.x, fmaf(crv.y, wrv.y, fmaf(crv.z, wrv.z, fmaf(crv.w, wrv.w, da))));
        db_ = fmaf(civ.x, wiv.x, fmaf(civ.y, wiv.y, fmaf(civ.z, wiv.z, fmaf(civ.w, wiv.w, db_))));
        dc = fmaf(civ.x, wrv.x, fmaf(civ.y, wrv.y, fmaf(civ.z, wrv.z, fmaf(civ.w, wrv.w, dc))));
        de = fmaf(crv.x, wiv.x, fmaf(crv.y, wiv.y, fmaf(crv.z, wiv.z, fmaf(crv.w, wiv.w, de))));
      }
      float brv = qbr[h * 64 + j], biv = qbi[h * 64 + j];
      qkL[2 * h][j] = da + brv - db_ - biv;
      qkL[2 * h + 1][j] = dc + brv + de + biv;
    } else if (tid < 224) {
      const int s2 = tid - 192;
      float a2 = 0.0f;
      for (int d = 0; d < 64; ++d)
        a2 = fmaf(memLr[s2 * 65 + d], zfmL[d], fmaf(memLi[s2 * 65 + d], zfmL[64 + d], a2));
      simL[s2] = a2;
    } else if (tid < 227) {
      const int h = tid - 224;
      float a2 = ab[h];
      for (int k2 = 0; k2 < 128; ++k2) a2 = fmaf(zfmL[k2], arbWL[h * 128 + k2], a2);
      scalL[3 + h] = a2;
    }
    __syncthreads();
    if (tid < 64) {
      float p = fmaf(qkL[0][tid], qkL[2][tid], qkL[1][tid] * qkL[3][tid]);
      p = wredsum(p);
      if (tid == 0) scalL[0] = 1.0f / (1.0f + expf(-p));
    } else if (tid < 96) {
      const int s2 = tid - 64;
      float v = simL[s2];
      float m = v;
#pragma unroll
      for (int msk = 16; msk > 0; msk >>= 1) m = fmaxf(m, __shfl_xor(m, msk));
      float e = expf(v - m);
      float ss = e;
#pragma unroll
      for (int msk = 16; msk > 0; msk >>= 1) ss += __shfl_xor(ss, msk);
      attnL[s2] = e / ss;
    } else if (tid == 96) {
      float a0 = scalL[3], a1 = scalL[4], a2 = scalL[5];
      float m = fmaxf(a0, fmaxf(a1, a2));
      float e0 = expf(a0 - m), e1 = expf(a1 - m), e2 = expf(a2 - m);
      float ssum = e0 + e1 + e2;
      scalL[3] = e0 / ssum; scalL[4] = e1 / ssum; scalL[5] = e2 / ssum;
    }
    __syncthreads();
    if (tid < 128) {
      const int d = ln;
      const float* ml = (wv == 0) ? memLr : memLi;
      float a2 = 0.0f;
#pragma unroll 4
      for (int s2 = 0; s2 < 32; ++s2) a2 = fmaf(attnL[s2], ml[s2 * 65 + d], a2);
      if (wv == 0) mrL[d] = a2; else miL[d] = a2;
    }
    // ---------- own-row tagged retry-read (detection folded into data) ----------
    while (true) {
      if (tid == 0) pollOK = 1u;
      __syncthreads();
      if (tid < 128) {
        u64 v = ld_coh64(&keys[(size_t)tid * 128 + blk]);
        if ((unsigned)((v >> 13) & 0x7FFFFull) != tag) pollOK = 0u;
        else kred[tid] = v;
      }
      __syncthreads();
      if (pollOK) break;
      __builtin_amdgcn_s_sleep(1);
    }
    // reduce 128 candidates -> own row's final key (tag preserved: min decided by d2 hi-word)
    if (tid < 64) {
      u64 a = kred[tid], b = kred[tid + 64];
      if (b < a) a = b;
#pragma unroll
      for (int m2 = 32; m2 > 0; m2 >>= 1) { u64 o = shflx64(a, m2); if (o < a) a = o; }
      if (tid == 0) st_coh64(&finalA[blk], a);
    }
    // ---------- finals tagged retry-read (all rows' results) ----------
    while (true) {
      if (tid == 0) pollOK = 1u;
      __syncthreads();
      if (tid < 128) {
        u64 v = ld_coh64(&finalA[tid]);
        if ((unsigned)((v >> 13) & 0x7FFFFull) != tag) pollOK = 0u;
        else key128L[tid] = v;
      }
      __syncthreads();
      if (pollOK) break;
      __builtin_amdgcn_s_sleep(1);
    }
    // ---------- consensus: idx + halt mask ----------
    if (tid < 128) {
      u64 key = key128L[tid];
      idxL[tid] = (unsigned)key & IDXM;
      float d2 = unpackd2(key);
      bool act_b = ((actM[tid >> 6] >> (tid & 63)) & 1ull) != 0ull;
      bool stop = (1.25f * 0.0078125f * d2) < hbias;
      u64 ball = __ballot(act_b && !stop);
      if (ln == 0) actN[tid >> 6] = ball;
    }
    __syncthreads();
    if (tid == 0) mfS = (unsigned)((actM[blk >> 6] >> (blk & 63)) & 1ull);
    if (tid < 2) actM[tid] = actN[tid];
    __syncthreads();
    const bool anyAct = (actN[0] | actN[1]) != 0ull;
    const bool mf = mfS != 0u;
    const unsigned ii = idxL[blk];
    if (tid < 128) {
      float zq = vqe[((size_t)ii << 7) + tid];
      zqL[tid] = zq;
      float df = zq - zfmL[tid];
      float sm = wredsum(df * df);
      if (ln == 0) vqpL[wv] = sm;
    } else if (tid < 256) {
      const int r = tid - 128;
      unsigned my = idxL[r];
      int c = 0;
#pragma unroll
      for (int j4 = 0; j4 < 32; ++j4) {
        uint4 q = *(const uint4*)&idxL[j4 * 4];
        c += (q.x == my) + (q.y == my) + (q.z == my) + (q.w == my);
      }
      float term = -0.0078125f * logf((float)c * 0.0078125f + 1e-10f);
      term = wredsum(term);
      if (ln == 0) entpL[wv - 2] = term;
    }
    __syncthreads();
    if (tid < 64) {
      const int d = tid;
      float gate = scalL[0], g0 = scalL[3], g1 = scalL[4], g2 = scalL[5];
      float cr = zfmL[d], ci = zfmL[64 + d];
      float ur = fmaf(g0, qkL[4][d] * gate, fmaf(g1, mrL[d], g2 * zqL[d]));
      float ui = fmaf(g0, qkL[5][d] * gate, fmaf(g1, miL[d], g2 * zqL[64 + d]));
      float cdr = fmaf(0.4f, ur, 0.6f * cr);
      float cdi = fmaf(0.4f, ui, 0.6f * ci);
      float ang = atan2f(cdi, cdr);
      float df = fabsf(ang - pangL[d]);
      df = fminf(df, TWO_PI_F - df);
      pangL[d] = ang;
      float dm = wredsum(df) * 0.015625f;
      if (mf) { gwrowL[d] = cdr; gwrowL[64 + d] = cdi; }
      if (d == 0) dmeanS = dm;
    }
    __syncthreads();
    const bool newT = !(anyAct && it < MAXREC - 1);
    const bool finished = newT && (t == TT - 1);
    if (newT && !finished) {
      float pr = 0.0f;
      if (tid < 128) {
        pr = gwrowL[tid];
        outhB[((size_t)blk * TT + t) * 128 + tid] = f2bf(pr);
        float part = wredsum(pr * gtwv);
        if (ln == 0) wsumL[wv] = part;
      }
      __syncthreads();
      if (tid < 128) {
        float wg = 1.0f / (1.0f + expf(-(wsumL[0] + wsumL[1] + gtb0)));
        int slot = 31 - t;
        float* m = (tid < 64) ? &memLr[slot * 65 + tid] : &memLi[slot * 65 + (tid - 64)];
        *m = fmaf(wg, pr, (1.0f - wg) * (*m));
        gwrowL[tid] = fmaf(alpha, pr, onema * encN);
      }
      __syncthreads();
    }
    if (!finished) {
      if (tid < 128) {
        float val = gwrowL[tid];
        float mu = wredsum(val) * 0.015625f;
        float xc = val - mu;
        float vr = wredsum(xc * xc) * 0.015625f;
        float z = xc * (1.0f / sqrtf(vr + 1e-5f)) * lnG + lnB;
        zfmL[tid] = z;
        st_coh_f32(&zbuf[(blk << 7) + tid], z);
      }
      drain_vm();
      __syncthreads();
      if (tid == 0) st_coh32(&zdone[blk * 4], k + 2u);
    } else {
      __syncthreads();
    }
    if (tid == 0) {
      float aold = mf ? 1.0f : 0.0f;
      float vql = 1.25f * (vqpL[0] + vqpL[1]) * 0.0078125f;
      accL[3] += aold * dmeanS;
      accL[2] += aold * 0.01f;
      if (mf) {
        accL[0] = vql;
        accL[1] = entpL[0] + entpL[1];
        dout[(size_t)LOGN + 4 + (size_t)blk * TT + t] = (float)ii;
      }
    }
    if (newT && !finished) {
      if (tid < 64) pangL[tid] = atan2f(gwrowL[64 + tid], gwrowL[tid]);
      if (tid < 4) { totL[tid] += accL[tid]; accL[tid] = 0.0f; }
      if (tid < 2) actM[tid] = ~0ull;
    }
    __syncthreads();
    if (finished) break;
    if (newT) { t++; it = 0; } else { it++; }
    k++;
  }

  // epilogue
  if (tid < 128) outhB[((size_t)blk * TT + (TT - 1)) * 128 + tid] = f2bf(gwrowL[tid]);
  if (tid < 4) rst[blk * 4 + tid] = totL[tid] + accL[tid];
  __syncthreads();
  if (tid == 0) st_coh32(&zdone[blk * 4], SENT);
}

// ================= MFMA decoder: 4096x8192x128 bf16 -> f32 =================
__global__ __launch_bounds__(256) void k_dec(
    const float* __restrict__ dbv, float* __restrict__ dout,
    const char* __restrict__ ws)
{
  const unsigned short* outhB = (const unsigned short*)(ws + OFF_OUTHB);
  const unsigned short* dWb = (const unsigned short*)(ws + OFF_DWB);
  const float* rst = (const float*)(ws + OFF_RST);
  const int tid = threadIdx.x;
  if (blockIdx.x == 0 && tid < 4) {
    float s = 0.0f;
    for (int r = 0; r < 128; ++r) s += rst[r * 4 + tid];
    dout[(size_t)LOGN + tid] = s * (1.0f / 4096.0f);
  }
  const int w = tid >> 6, l = tid & 63;
  const int bm = blockIdx.x & 63;
  const int bn = blockIdx.x >> 6;
  const int ar = l & 15, kg = l >> 4;
  const int m_base = bm * 64;
  const int n_base = bn * 256 + w * 64;
  f32x4 acc[4][4];
#pragma unroll
  for (int mt = 0; mt < 4; ++mt)
#pragma unroll
    for (int nt = 0; nt < 4; ++nt) acc[mt][nt] = (f32x4){0.f, 0.f, 0.f, 0.f};
#pragma unroll
  for (int kc = 0; kc < 4; ++kc) {
    const int ko = kc * 32 + kg * 8;
    bf16x8 a[4], b[4];
#pragma unroll
    for (int mt = 0; mt < 4; ++mt)
      a[mt] = *(const bf16x8*)(outhB + (size_t)(m_base + mt * 16 + ar) * 128 + ko);
#pragma unroll
    for (int nt = 0; nt < 4; ++nt)
      b[nt] = *(const bf16x8*)(dWb + (size_t)(n_base + nt * 16 + ar) * 128 + ko);
#pragma unroll
    for (int mt = 0; mt < 4; ++mt)
#pragma unroll
      for (int nt = 0; nt < 4; ++nt)
        acc[mt][nt] = __builtin_amdgcn_mfma_f32_16x16x32_bf16(a[mt], b[nt], acc[mt][nt], 0, 0, 0);
  }
#pragma unroll
  for (int nt = 0; nt < 4; ++nt) {
    const int n = n_base + nt * 16 + ar;
    const float bv = dbv[n];
#pragma unroll
    for (int mt = 0; mt < 4; ++mt) {
#pragma unroll
      for (int rr = 0; rr < 4; ++rr) {
        const int m = m_base + mt * 16 + kg * 4 + rr;
        dout[(size_t)m * 8192 + n] = acc[mt][nt][rr] + bv;
      }
    }
  }
}

extern "C" void kernel_launch(void* const* d_in, const int* in_sizes, int n_in,
                              void* d_out, int out_size, void* d_ws, size_t ws_size,
                              hipStream_t stream) {
  (void)in_sizes; (void)n_in; (void)out_size; (void)ws_size;
  const int*   x_seq = (const int*)d_in[0];
  const float* enc = (const float*)d_in[1];
  const float* vq  = (const float*)d_in[2];
  const float* nrg = (const float*)d_in[3];
  const float* nrb = (const float*)d_in[4];
  const float* nig = (const float*)d_in[5];
  const float* nib = (const float*)d_in[6];
  const float* qWr = (const float*)d_in[7];
  const float* qbr = (const float*)d_in[8];
  const float* qWi = (const float*)d_in[9];
  const float* qbi = (const float*)d_in[10];
  const float* gtw = (const float*)d_in[11];
  const float* gtb = (const float*)d_in[12];
  const float* aW  = (const float*)d_in[13];
  const float* ab  = (const float*)d_in[14];
  const float* dW  = (const float*)d_in[15];
  const float* db  = (const float*)d_in[16];
  const float* hb  = (const float*)d_in[17];
  const float* ig  = (const float*)d_in[18];
  char* ws = (char*)d_ws;
  float* out = (float*)d_out;
  hipLaunchKernelGGL(sacrsn_init, dim3(1), dim3(512), 0, stream, ws);
  hipLaunchKernelGGL(k_prep, dim3(1024), dim3(256), 0, stream, dW, ws);
  hipLaunchKernelGGL(sacrsn_main, dim3(NBLK), dim3(NTHR), 0, stream,
                     x_seq, enc, vq, nrg, nrb, nig, nib, qWr, qbr, qWi, qbi,
                     gtw, gtb, aW, ab, hb, ig, out, ws);
  hipLaunchKernelGGL(k_dec, dim3(2048), dim3(256), 0, stream, db, out, ws);
}

// Round 11
// 698.042 us; speedup vs baseline: 1.6479x; 1.0583x over previous
//
#include <hip/hip_runtime.h>
#include <math.h>

#define TT 32
#define MAXREC 8
#define NBLK 256
#define NTHR 512

// workspace byte offsets
#define OFF_ZBUF   0u          // 128*128 f32 = 65536 (exact z rows)
#define OFF_ZBUFB  65536u      // 128*128 bf16 = 32768 (z rows for MFMA)
#define OFF_KEYS   98304u      // 128 servers * 128 rows * 8B (tag-embedded)
#define OFF_ZDONE  229376u     // 128 * 16B tagged u64 {lo=tag, hi=z2 bits}
#define OFF_ESQ    231424u     // 8192 f32 exact |e|^2
#define OFF_RST    264192u     // 128*4 f32
#define OFF_OUTHB  266240u     // 4096*128 bf16 = 1048576
#define OFF_WB     1314816u    // 2 MB: vqeB (main) then dWb (k_dec)

#define SENT 0x7FFFFFFFu
#define IDXM 0x1FFFu
#define LOGN 33554432u        // 128*32*8192
#define TWO_PI_F 6.283185307179586f

typedef float f32x4 __attribute__((ext_vector_type(4)));
typedef short bf16x8 __attribute__((ext_vector_type(8)));
typedef unsigned long long u64;

__device__ __forceinline__ float wredsum(float v) {
#pragma unroll
  for (int m = 32; m > 0; m >>= 1) v += __shfl_xor(v, m);
  return v;
}
__device__ __forceinline__ u64 shflx64(u64 v, int m) {
  int lo = __shfl_xor((int)(unsigned)(v & 0xffffffffull), m);
  int hi = __shfl_xor((int)(unsigned)(v >> 32), m);
  return ((u64)(unsigned)hi << 32) | (unsigned)lo;
}
// monotone float->u32 + 13-bit idx: u64-min == (min dist, then min idx)
__device__ __forceinline__ u64 packkey(float d, unsigned c) {
  unsigned u = __float_as_uint(d);
  u = (u & 0x80000000u) ? ~u : (u | 0x80000000u);
  return ((u64)u << 32) | c;
}
__device__ __forceinline__ float unpackd2(u64 key) {
  unsigned hi = (unsigned)(key >> 32);
  unsigned orig = (hi & 0x80000000u) ? (hi & 0x7fffffffu) : ~hi;
  return __uint_as_float(orig);
}
__device__ __forceinline__ unsigned short f2bf(float f) {
  unsigned u = __float_as_uint(f);
  unsigned r = (u >> 16) & 1u;
  u += 0x7fffu + r;
  return (unsigned short)(u >> 16);
}

// ---- coherent (cross-XCD, L2-bypass) accesses ----
__device__ __forceinline__ u64 ld_coh64(const u64* p) {
  u64 v;
  asm volatile("global_load_dwordx2 %0, %1, off sc0 sc1\n\ts_waitcnt vmcnt(0)"
               : "=&v"(v) : "v"(p) : "memory");
  return v;
}
__device__ __forceinline__ void st_coh_f32(float* p, float v) {
  asm volatile("global_store_dword %0, %1, off sc0 sc1" :: "v"(p), "v"(v) : "memory");
}
__device__ __forceinline__ void st_coh32(unsigned* p, unsigned v) {
  asm volatile("global_store_dword %0, %1, off sc0 sc1" :: "v"(p), "v"(v) : "memory");
}
__device__ __forceinline__ void st_coh64(u64* p, u64 v) {
  asm volatile("global_store_dwordx2 %0, %1, off sc0 sc1" :: "v"(p), "v"(v) : "memory");
}
__device__ __forceinline__ void drain_vm() {
  asm volatile("s_waitcnt vmcnt(0)" ::: "memory");
}
// 4 coherent 16B loads + wait (single round trip); byte offsets from base
__device__ __forceinline__ void ld4w(const float* base,
    unsigned o0, unsigned o1, unsigned o2, unsigned o3,
    f32x4& a0, f32x4& a1, f32x4& a2, f32x4& a3) {
  asm volatile(
      "global_load_dwordx4 %0, %4, %8 sc0 sc1\n\t"
      "global_load_dwordx4 %1, %5, %8 sc0 sc1\n\t"
      "global_load_dwordx4 %2, %6, %8 sc0 sc1\n\t"
      "global_load_dwordx4 %3, %7, %8 sc0 sc1\n\t"
      "s_waitcnt vmcnt(0)"
      : "=&v"(a0), "=&v"(a1), "=&v"(a2), "=&v"(a3)
      : "v"(o0), "v"(o1), "v"(o2), "v"(o3), "s"(base)
      : "memory");
}

__global__ __launch_bounds__(512) void sacrsn_init(char* __restrict__ ws) {
  u64* zd = (u64*)(ws + OFF_ZDONE);
  u64* fin = (u64*)(ws + OFF_KEYS);   // zero tags of keys not required; zero zdone
  (void)fin;
  if (threadIdx.x < 256) ((u64*)zd)[threadIdx.x] = 0ull;  // 128 * 16B
}

// vq_emb f32 -> bf16 (WB) + exact esq
__global__ __launch_bounds__(256) void k_prepv(const float* __restrict__ vqe,
                                               char* __restrict__ ws) {
  unsigned short* vqeB = (unsigned short*)(ws + OFF_WB);
  float* esqG = (float*)(ws + OFF_ESQ);
  const int i = (blockIdx.x * 256 + threadIdx.x) * 4;
  float4 v = *(const float4*)(vqe + i);
  ushort4 o;
  o.x = f2bf(v.x); o.y = f2bf(v.y); o.z = f2bf(v.z); o.w = f2bf(v.w);
  *(ushort4*)(vqeB + i) = o;
  if (blockIdx.x < 32) {
    const int c = blockIdx.x * 256 + threadIdx.x;
    const float4* e = (const float4*)(vqe + ((size_t)c << 7));
    float s = 0.f;
#pragma unroll 8
    for (int k4 = 0; k4 < 32; ++k4) {
      float4 q = e[k4];
      s = fmaf(q.x, q.x, fmaf(q.y, q.y, fmaf(q.z, q.z, fmaf(q.w, q.w, s))));
    }
    esqG[c] = s;
  }
}

// dec_W f32 -> bf16 (WB), runs AFTER main
__global__ __launch_bounds__(256) void k_prepd(const float* __restrict__ dW,
                                               char* __restrict__ ws) {
  unsigned short* dWb = (unsigned short*)(ws + OFF_WB);
  const int i = (blockIdx.x * 256 + threadIdx.x) * 4;
  float4 v = *(const float4*)(dW + i);
  ushort4 o;
  o.x = f2bf(v.x); o.y = f2bf(v.y); o.z = f2bf(v.z); o.w = f2bf(v.w);
  *(ushort4*)(dWb + i) = o;
}

__global__ __launch_bounds__(NTHR) void sacrsn_main(
    const int* __restrict__ x_seq, const float* __restrict__ enc,
    const float* __restrict__ vqe,
    const float* __restrict__ nrg, const float* __restrict__ nrb,
    const float* __restrict__ nig, const float* __restrict__ nib,
    const float* __restrict__ qWr, const float* __restrict__ qbr,
    const float* __restrict__ qWi, const float* __restrict__ qbi,
    const float* __restrict__ gtw, const float* __restrict__ gtb,
    const float* __restrict__ aW, const float* __restrict__ ab,
    const float* __restrict__ hbp, const float* __restrict__ igp,
    float* __restrict__ dout, char* __restrict__ ws)
{
  float* zbuf = (float*)(ws + OFF_ZBUF);
  unsigned* zbufB32 = (unsigned*)(ws + OFF_ZBUFB);
  u64*   keys = (u64*)(ws + OFF_KEYS);
  u64*   zdone64 = (u64*)(ws + OFF_ZDONE);
  const float* esqG = (const float*)(ws + OFF_ESQ);
  const unsigned short* vqeB = (const unsigned short*)(ws + OFF_WB);
  u64*   finalA = (u64*)(ws + OFF_KEYS);  // reuse first 1KB? NO — separate region needed
  unsigned short* outhB = (unsigned short*)(ws + OFF_OUTHB);
  float* rst  = (float*)(ws + OFF_RST);
  // finals live in the last 1KB of ZDONE region? keep separate: use tail of ESQ region? No.
  // Use a dedicated slot: place finals in OFF_ZDONE + 2048 .. +3072 (within the 2KB gap to ESQ).
  finalA = (u64*)(ws + OFF_ZDONE + 1024u);  // bytes 229376+1024 .. +2048 (zdone uses 16B*128=2048!)
  // zdone uses 2048 bytes fully; instead place finals right before ESQ is NOT free.
  // Correct: put finals inside KEYS tail is unsafe. Use OFF_RST region? rst is 2048B but only 2048 used.
  // Allocate finals at OFF_RST + 2048? RST region is 2048B (OFF_OUTHB - OFF_RST = 2048). 
  // SAFE spot: OFF_ESQ + 32768 .. OFF_RST (264192-264192=0). Gap check: ESQ ends 231424+32768=264192=OFF_RST. none.
  // Use ZBUFB tail: zbufB uses 32768 fully. Use ZBUF tail: zbuf uses 65536 fully.
  // => shift: finals overlay the UNUSED upper half of ZDONE stride-16 slots (8B used of each 16B).
  finalA = (u64*)(ws + OFF_ZDONE + 8u);   // entry r at ZDONE + r*16 + 8 (upper 8B of each slot)

  const int tid = threadIdx.x;
  const int wv = tid >> 6, ln = tid & 63;
  const int blk = blockIdx.x;
  const bool owner = (blk < 128);

  // ---- LDS ----
  __shared__ float memLr[32 * 65];
  __shared__ float memLi[32 * 65];
  __shared__ float gwrowL[128], pangL[64], zfmL[128], zqL[128];
  __shared__ float qkL[6][64], simL[32], attnL[32], mrL[64], miL[64];
  __shared__ unsigned idxL[128] __attribute__((aligned(16)));
  __shared__ u64 key128L[128], kred[128];
  __shared__ float arbWL[3 * 128];
  __shared__ float scalL[8], entpL[2], vqpL[2], wsumL[2], z2pL[2];
  __shared__ float accL[4], totL[4];
  __shared__ float dmeanS;
  __shared__ u64 actM[2], actN[2];
  __shared__ unsigned pollOK, pollSent, mfS;
  // server-side
  __shared__ float z2L[128], sz2L[128];
  __shared__ u64 rowminU[128];
  __shared__ unsigned candL[8192];
  __shared__ unsigned candCount;

  const float alpha = 1.0f / (1.0f + expf(-igp[0]));
  const float onema = 1.0f - alpha;
  const float hbias = log1pf(expf(hbp[0]));
  const float gtb0 = gtb[0];

  if (!owner) {
    // ================= VQ server: blocks 128..255, 64 codes, MFMA + exact rescue =================
    const int s = blk - 128;
    const int w = tid >> 6, l = tid & 63;      // 8 waves: wave w owns rows w*16..w*16+15
    const int ar = l & 15, kg = l >> 4;
    unsigned k = 0;
    while (true) {
      bool done = false;
      while (true) {
        if (tid == 0) { pollOK = 1u; pollSent = 1u; }
        __syncthreads();
        if (tid < 128) {
          u64 v = ld_coh64(&zdone64[tid * 2]);
          unsigned lo = (unsigned)v;
          if ((int)(lo - (k + 1u)) < 0) pollOK = 0u;
          if (lo != SENT) pollSent = 0u;
          if (lo == k + 1u) z2L[tid] = __uint_as_float((unsigned)(v >> 32));
        }
        __syncthreads();
        if (pollSent) { done = true; break; }
        if (pollOK) break;
        __builtin_amdgcn_s_sleep(1);
      }
      if (done) break;
      if (tid < 128) { sz2L[tid] = sqrtf(z2L[tid]); rowminU[tid] = ~0ull; }
      if (tid == 0) candCount = 0u;
      __syncthreads();
      // ---- MFMA approx dots: rows (w*16..+15) x 64 codes, K=128 ----
      f32x4 af0, af1, af2, af3;
      {
        const unsigned rb = (unsigned)((w * 16 + ar) * 256 + kg * 16);
        ld4w((const float*)(ws + OFF_ZBUFB), rb, rb + 64u, rb + 128u, rb + 192u,
             af0, af1, af2, af3);
      }
      bf16x8 afr[4];
      afr[0] = *(bf16x8*)&af0; afr[1] = *(bf16x8*)&af1;
      afr[2] = *(bf16x8*)&af2; afr[3] = *(bf16x8*)&af3;
      f32x4 dc[4];
#pragma unroll
      for (int nt = 0; nt < 4; ++nt) dc[nt] = (f32x4){0.f, 0.f, 0.f, 0.f};
#pragma unroll
      for (int kc = 0; kc < 4; ++kc) {
#pragma unroll
        for (int nt = 0; nt < 4; ++nt) {
          bf16x8 b = *(const bf16x8*)(vqeB + (((size_t)(s * 64 + nt * 16 + ar)) << 7)
                                      + kc * 32 + kg * 8);
          dc[nt] = __builtin_amdgcn_mfma_f32_16x16x32_bf16(afr[kc], b, dc[nt], 0, 0, 0);
        }
      }
      // ---- epilogue: a, e, per-row L=min(a+e), candidates ----
      float aV[4][4], eV[4][4], Lmin[4];
#pragma unroll
      for (int rr = 0; rr < 4; ++rr) Lmin[rr] = 1e30f;
#pragma unroll
      for (int nt = 0; nt < 4; ++nt) {
        const int code = s * 64 + nt * 16 + ar;
        const float es = esqG[code];
        const float se = sqrtf(es);
#pragma unroll
        for (int rr = 0; rr < 4; ++rr) {
          const int row = w * 16 + kg * 4 + rr;
          float av = (z2L[row] - 2.0f * dc[nt][rr]) + es;
          float ev = fmaf(0.0082f * sz2L[row], se, 1e-3f);
          aV[nt][rr] = av; eV[nt][rr] = ev;
          float ae = av + ev;
          if (ae < Lmin[rr]) Lmin[rr] = ae;
        }
      }
#pragma unroll
      for (int m2 = 1; m2 < 16; m2 <<= 1)
#pragma unroll
        for (int rr = 0; rr < 4; ++rr) {
          float o = __shfl_xor(Lmin[rr], m2);
          if (o < Lmin[rr]) Lmin[rr] = o;
        }
#pragma unroll
      for (int nt = 0; nt < 4; ++nt)
#pragma unroll
        for (int rr = 0; rr < 4; ++rr)
          if (aV[nt][rr] - eV[nt][rr] <= Lmin[rr]) {
            const unsigned row = (unsigned)(w * 16 + kg * 4 + rr);
            const unsigned code = (unsigned)(s * 64 + nt * 16 + ar);
            unsigned pos = atomicAdd(&candCount, 1u);
            candL[pos] = (row << 16) | code;
          }
      __syncthreads();
      // ---- exact f32 rescue: 8 lanes per entry ----
      const unsigned cnt = candCount;
      for (unsigned base = 0; base < cnt; base += 64u) {
        const unsigned eIdx = base + (unsigned)(tid >> 3);
        const bool valid = eIdx < cnt;
        float dsum = 0.f;
        int row = 0, code = 0;
        if (valid) {
          unsigned en = candL[eIdx];
          row = (int)(en >> 16); code = (int)(en & 0xFFFFu);
          const int ks = tid & 7;
          f32x4 z0, z1, z2v, z3;
          const unsigned zb = (unsigned)(row * 512 + ks * 64);
          ld4w(zbuf, zb, zb + 16u, zb + 32u, zb + 48u, z0, z1, z2v, z3);
          const float4* ep = (const float4*)(vqe + ((size_t)code << 7) + ks * 16);
          float4 e0 = ep[0], e1 = ep[1], e2 = ep[2], e3 = ep[3];
          dsum = fmaf(z0[0], e0.x, fmaf(z0[1], e0.y, fmaf(z0[2], e0.z, fmaf(z0[3], e0.w, 0.f))));
          dsum = fmaf(z1[0], e1.x, fmaf(z1[1], e1.y, fmaf(z1[2], e1.z, fmaf(z1[3], e1.w, dsum))));
          dsum = fmaf(z2v[0], e2.x, fmaf(z2v[1], e2.y, fmaf(z2v[2], e2.z, fmaf(z2v[3], e2.w, dsum))));
          dsum = fmaf(z3[0], e3.x, fmaf(z3[1], e3.y, fmaf(z3[2], e3.z, fmaf(z3[3], e3.w, dsum))));
        }
#pragma unroll
        for (int m2 = 1; m2 < 8; m2 <<= 1) dsum += __shfl_xor(dsum, m2);
        if (valid && (tid & 7) == 0) {
          float d2 = (z2L[row] - 2.0f * dsum) + esqG[code];
          atomicMin(&rowminU[row], packkey(d2, (unsigned)code));
        }
      }
      __syncthreads();
      if (tid < 128)
        st_coh64(&keys[(size_t)s * 128 + tid], rowminU[tid] | ((u64)(k + 1u) << 13));
      k++;
    }
    return;
  }

  // ================= owner: blocks 0..127, row = blk =================
  float lnG = 0.0f, lnB = 0.0f, gtwv = 0.0f;
  if (tid < 64) { lnG = nrg[tid]; lnB = nrb[tid]; }
  else if (tid < 128) { lnG = nig[tid - 64]; lnB = nib[tid - 64]; }
  if (tid < 128) gtwv = gtw[tid];
  for (int i = tid; i < 32 * 65; i += NTHR) { memLr[i] = 0.0f; memLi[i] = 0.0f; }
  if (tid < 4) { totL[tid] = 0.0f; accL[tid] = 0.0f; }
  if (tid < 2) actM[tid] = ~0ull;
  for (int i = tid; i < 384; i += NTHR) arbWL[i] = aW[i];
  {
    int tok = x_seq[blk * TT];
    if (tid < 128) gwrowL[tid] = onema * enc[((size_t)tok << 7) + tid];
  }
  __syncthreads();
  if (tid < 64) pangL[tid] = atan2f(gwrowL[64 + tid], gwrowL[tid]);
  if (tid < 128) {
    float val = gwrowL[tid];
    float mu = wredsum(val) * 0.015625f;
    float xc = val - mu;
    float vr = wredsum(xc * xc) * 0.015625f;
    float z = xc * (1.0f / sqrtf(vr + 1e-5f)) * lnG + lnB;
    zfmL[tid] = z;
    st_coh_f32(&zbuf[(blk << 7) + tid], z);
    float zo = __shfl_xor(z, 1);
    if ((tid & 1) == 0) {
      unsigned pk = (unsigned)f2bf(z) | ((unsigned)f2bf(zo) << 16);
      st_coh32(&zbufB32[blk * 64 + (tid >> 1)], pk);
    }
    float s2 = wredsum(z * z);
    if (ln == 0) z2pL[wv] = s2;
  }
  drain_vm();
  __syncthreads();
  if (tid == 0) {
    float z2 = z2pL[0] + z2pL[1];
    st_coh64(&zdone64[blk * 2], (u64)1u | ((u64)__float_as_uint(z2) << 32));
  }

  int t = 0, it = 0;
  unsigned k = 0;
  for (;;) {
    const unsigned tag = k + 1u;
    float encN = 0.0f;
    {
      int tnext = (t + 1 < TT) ? t + 1 : t;
      if (tid < 128) {
        int tk = x_seq[blk * TT + tnext];
        encN = enc[((size_t)tk << 7) + tid];
      }
    }
    // ---------- C-prep on zfmL (overlaps server work) ----------
    if (tid < 192) {
      const int h = tid >> 6, j = tid & 63;
      const float* wr = qWr + h * 4096 + j * 64;
      const float* wi = qWi + h * 4096 + j * 64;
      float da = 0.0f, db_ = 0.0f, dc2 = 0.0f, de = 0.0f;
#pragma unroll 4
      for (int d4 = 0; d4 < 64; d4 += 4) {
        float4 wrv = *(const float4*)&wr[d4];
        float4 wiv = *(const float4*)&wi[d4];
        float4 crv = *(const float4*)&zfmL[d4];
        float4 civ = *(const float4*)&zfmL[64 + d4];
        da = fmaf(crv.x, wrv.x, fmaf(crv.y, wrv.y, fmaf(crv.z, wrv.z, fmaf(crv.w, wrv.w, da))));
        db_ = fmaf(civ.x, wiv.x, fmaf(civ.y, wiv.y, fmaf(civ.z, wiv.z, fmaf(civ.w, wiv.w, db_))));
        dc2 = fmaf(civ.x, wrv.x, fmaf(civ.y, wrv.y, fmaf(civ.z, wrv.z, fmaf(civ.w, wrv.w, dc2))));
        de = fmaf(crv.x, wiv.x, fmaf(crv.y, wiv.y, fmaf(crv.z, wiv.z, fmaf(crv.w, wiv.w, de))));
      }
      float brv = qbr[h * 64 + j], biv = qbi[h * 64 + j];
      qkL[2 * h][j] = da + brv - db_ - biv;
      qkL[2 * h + 1][j] = dc2 + brv + de + biv;
    } else if (tid < 224) {
      const int s2 = tid - 192;
      float a2 = 0.0f;
      for (int d = 0; d < 64; ++d)
        a2 = fmaf(memLr[s2 * 65 + d], zfmL[d], fmaf(memLi[s2 * 65 + d], zfmL[64 + d], a2));
      simL[s2] = a2;
    } else if (tid < 227) {
      const int h = tid - 224;
      float a2 = ab[h];
      for (int k2 = 0; k2 < 128; ++k2) a2 = fmaf(zfmL[k2], arbWL[h * 128 + k2], a2);
      scalL[3 + h] = a2;
    }
    __syncthreads();
    if (tid < 64) {
      float p = fmaf(qkL[0][tid], qkL[2][tid], qkL[1][tid] * qkL[3][tid]);
      p = wredsum(p);
      if (tid == 0) scalL[0] = 1.0f / (1.0f + expf(-p));
    } else if (tid < 96) {
      const int s2 = tid - 64;
      float v = simL[s2];
      float m = v;
#pragma unroll
      for (int msk = 16; msk > 0; msk >>= 1) m = fmaxf(m, __shfl_xor(m, msk));
      float e = expf(v - m);
      float ss = e;
#pragma unroll
      for (int msk = 16; msk > 0; msk >>= 1) ss += __shfl_xor(ss, msk);
      attnL[s2] = e / ss;
    } else if (tid == 96) {
      float a0 = scalL[3], a1 = scalL[4], a2 = scalL[5];
      float m = fmaxf(a0, fmaxf(a1, a2));
      float e0 = expf(a0 - m), e1 = expf(a1 - m), e2 = expf(a2 - m);
      float ssum = e0 + e1 + e2;
      scalL[3] = e0 / ssum; scalL[4] = e1 / ssum; scalL[5] = e2 / ssum;
    }
    __syncthreads();
    if (tid < 128) {
      const int d = ln;
      const float* ml = (wv == 0) ? memLr : memLi;
      float a2 = 0.0f;
#pragma unroll 4
      for (int s2 = 0; s2 < 32; ++s2) a2 = fmaf(attnL[s2], ml[s2 * 65 + d], a2);
      if (wv == 0) mrL[d] = a2; else miL[d] = a2;
    }
    // ---------- own-row tagged retry-read ----------
    while (true) {
      if (tid == 0) pollOK = 1u;
      __syncthreads();
      if (tid < 128) {
        u64 v = ld_coh64(&keys[(size_t)tid * 128 + blk]);
        if ((unsigned)((v >> 13) & 0x7FFFFull) != tag) pollOK = 0u;
        else kred[tid] = v;
      }
      __syncthreads();
      if (pollOK) break;
      __builtin_amdgcn_s_sleep(1);
    }
    if (tid < 64) {
      u64 a = kred[tid], b = kred[tid + 64];
      if (b < a) a = b;
#pragma unroll
      for (int m2 = 32; m2 > 0; m2 >>= 1) { u64 o = shflx64(a, m2); if (o < a) a = o; }
      if (tid == 0) st_coh64(&finalA[blk * 2], a);
    }
    while (true) {
      if (tid == 0) pollOK = 1u;
      __syncthreads();
      if (tid < 128) {
        u64 v = ld_coh64(&finalA[tid * 2]);
        if ((unsigned)((v >> 13) & 0x7FFFFull) != tag) pollOK = 0u;
        else key128L[tid] = v;
      }
      __syncthreads();
      if (pollOK) break;
      __builtin_amdgcn_s_sleep(1);
    }
    // ---------- consensus ----------
    if (tid < 128) {
      u64 key = key128L[tid];
      idxL[tid] = (unsigned)key & IDXM;
      float d2 = unpackd2(key);
      bool act_b = ((actM[tid >> 6] >> (tid & 63)) & 1ull) != 0ull;
      bool stop = (1.25f * 0.0078125f * d2) < hbias;
      u64 ball = __ballot(act_b && !stop);
      if (ln == 0) actN[tid >> 6] = ball;
    }
    __syncthreads();
    if (tid == 0) mfS = (unsigned)((actM[blk >> 6] >> (blk & 63)) & 1ull);
    if (tid < 2) actM[tid] = actN[tid];
    __syncthreads();
    const bool anyAct = (actN[0] | actN[1]) != 0ull;
    const bool mf = mfS != 0u;
    const unsigned ii = idxL[blk];
    if (tid < 128) {
      float zq = vqe[((size_t)ii << 7) + tid];
      zqL[tid] = zq;
      float df = zq - zfmL[tid];
      float sm = wredsum(df * df);
      if (ln == 0) vqpL[wv] = sm;
    } else if (tid < 256) {
      const int r = tid - 128;
      unsigned my = idxL[r];
      int c = 0;
#pragma unroll
      for (int j4 = 0; j4 < 32; ++j4) {
        uint4 q = *(const uint4*)&idxL[j4 * 4];
        c += (q.x == my) + (q.y == my) + (q.z == my) + (q.w == my);
      }
      float term = -0.0078125f * logf((float)c * 0.0078125f + 1e-10f);
      term = wredsum(term);
      if (ln == 0) entpL[wv - 2] = term;
    }
    __syncthreads();
    if (tid < 64) {
      const int d = tid;
      float gate = scalL[0], g0 = scalL[3], g1 = scalL[4], g2 = scalL[5];
      float cr = zfmL[d], ci = zfmL[64 + d];
      float ur = fmaf(g0, qkL[4][d] * gate, fmaf(g1, mrL[d], g2 * zqL[d]));
      float ui = fmaf(g0, qkL[5][d] * gate, fmaf(g1, miL[d], g2 * zqL[64 + d]));
      float cdr = fmaf(0.4f, ur, 0.6f * cr);
      float cdi = fmaf(0.4f, ui, 0.6f * ci);
      float ang = atan2f(cdi, cdr);
      float df = fabsf(ang - pangL[d]);
      df = fminf(df, TWO_PI_F - df);
      pangL[d] = ang;
      float dm = wredsum(df) * 0.015625f;
      if (mf) { gwrowL[d] = cdr; gwrowL[64 + d] = cdi; }
      if (d == 0) dmeanS = dm;
    }
    __syncthreads();
    const bool newT = !(anyAct && it < MAXREC - 1);
    const bool finished = newT && (t == TT - 1);
    if (newT && !finished) {
      float pr = 0.0f;
      if (tid < 128) {
        pr = gwrowL[tid];
        outhB[((size_t)blk * TT + t) * 128 + tid] = f2bf(pr);
        float part = wredsum(pr * gtwv);
        if (ln == 0) wsumL[wv] = part;
      }
      __syncthreads();
      if (tid < 128) {
        float wg = 1.0f / (1.0f + expf(-(wsumL[0] + wsumL[1] + gtb0)));
        int slot = 31 - t;
        float* m = (tid < 64) ? &memLr[slot * 65 + tid] : &memLi[slot * 65 + (tid - 64)];
        *m = fmaf(wg, pr, (1.0f - wg) * (*m));
        gwrowL[tid] = fmaf(alpha, pr, onema * encN);
      }
      __syncthreads();
    }
    if (!finished) {
      if (tid < 128) {
        float val = gwrowL[tid];
        float mu = wredsum(val) * 0.015625f;
        float xc = val - mu;
        float vr = wredsum(xc * xc) * 0.015625f;
        float z = xc * (1.0f / sqrtf(vr + 1e-5f)) * lnG + lnB;
        zfmL[tid] = z;
        st_coh_f32(&zbuf[(blk << 7) + tid], z);
        float zo = __shfl_xor(z, 1);
        if ((tid & 1) == 0) {
          unsigned pk = (unsigned)f2bf(z) | ((unsigned)f2bf(zo) << 16);
          st_coh32(&zbufB32[blk * 64 + (tid >> 1)], pk);
        }
        float s2 = wredsum(z * z);
        if (ln == 0) z2pL[wv] = s2;
      }
      drain_vm();
      __syncthreads();
      if (tid == 0) {
        float z2 = z2pL[0] + z2pL[1];
        st_coh64(&zdone64[blk * 2], (u64)(k + 2u) | ((u64)__float_as_uint(z2) << 32));
      }
    } else {
      __syncthreads();
    }
    if (tid == 0) {
      float aold = mf ? 1.0f : 0.0f;
      float vql = 1.25f * (vqpL[0] + vqpL[1]) * 0.0078125f;
      accL[3] += aold * dmeanS;
      accL[2] += aold * 0.01f;
      if (mf) {
        accL[0] = vql;
        accL[1] = entpL[0] + entpL[1];
        dout[(size_t)LOGN + 4 + (size_t)blk * TT + t] = (float)ii;
      }
    }
    if (newT && !finished) {
      if (tid < 64) pangL[tid] = atan2f(gwrowL[64 + tid], gwrowL[tid]);
      if (tid < 4) { totL[tid] += accL[tid]; accL[tid] = 0.0f; }
      if (tid < 2) actM[tid] = ~0ull;
    }
    __syncthreads();
    if (finished) break;
    if (newT) { t++; it = 0; } else { it++; }
    k++;
  }

  // epilogue
  if (tid < 128) outhB[((size_t)blk * TT + (TT - 1)) * 128 + tid] = f2bf(gwrowL[tid]);
  if (tid < 4) rst[blk * 4 + tid] = totL[tid] + accL[tid];
  __syncthreads();
  if (tid == 0) st_coh64(&zdone64[blk * 2], (u64)SENT);
}

// ================= MFMA decoder: 4096x8192x128 bf16 -> f32 =================
__global__ __launch_bounds__(256) void k_dec(
    const float* __restrict__ dbv, float* __restrict__ dout,
    const char* __restrict__ ws)
{
  const unsigned short* outhB = (const unsigned short*)(ws + OFF_OUTHB);
  const unsigned short* dWb = (const unsigned short*)(ws + OFF_WB);
  const float* rst = (const float*)(ws + OFF_RST);
  const int tid = threadIdx.x;
  if (blockIdx.x == 0 && tid < 4) {
    float s = 0.0f;
    for (int r = 0; r < 128; ++r) s += rst[r * 4 + tid];
    dout[(size_t)LOGN + tid] = s * (1.0f / 4096.0f);
  }
  const int w = tid >> 6, l = tid & 63;
  const int bm = blockIdx.x & 63;
  const int bn = blockIdx.x >> 6;
  const int ar = l & 15, kg = l >> 4;
  const int m_base = bm * 64;
  const int n_base = bn * 256 + w * 64;
  f32x4 acc[4][4];
#pragma unroll
  for (int mt = 0; mt < 4; ++mt)
#pragma unroll
    for (int nt = 0; nt < 4; ++nt) acc[mt][nt] = (f32x4){0.f, 0.f, 0.f, 0.f};
#pragma unroll
  for (int kc = 0; kc < 4; ++kc) {
    const int ko = kc * 32 + kg * 8;
    bf16x8 a[4], b[4];
#pragma unroll
    for (int mt = 0; mt < 4; ++mt)
      a[mt] = *(const bf16x8*)(outhB + (size_t)(m_base + mt * 16 + ar) * 128 + ko);
#pragma unroll
    for (int nt = 0; nt < 4; ++nt)
      b[nt] = *(const bf16x8*)(dWb + (size_t)(n_base + nt * 16 + ar) * 128 + ko);
#pragma unroll
    for (int mt = 0; mt < 4; ++mt)
#pragma unroll
      for (int nt = 0; nt < 4; ++nt)
        acc[mt][nt] = __builtin_amdgcn_mfma_f32_16x16x32_bf16(a[mt], b[nt], acc[mt][nt], 0, 0, 0);
  }
#pragma unroll
  for (int nt = 0; nt < 4; ++nt) {
    const int n = n_base + nt * 16 + ar;
    const float bv = dbv[n];
#pragma unroll
    for (int mt = 0; mt < 4; ++mt) {
#pragma unroll
      for (int rr = 0; rr < 4; ++rr) {
        const int m = m_base + mt * 16 + kg * 4 + rr;
        dout[(size_t)m * 8192 + n] = acc[mt][nt][rr] + bv;
      }
    }
  }
}

extern "C" void kernel_launch(void* const* d_in, const int* in_sizes, int n_in,
                              void* d_out, int out_size, void* d_ws, size_t ws_size,
                              hipStream_t stream) {
  (void)in_sizes; (void)n_in; (void)out_size; (void)ws_size;
  const int*   x_seq = (const int*)d_in[0];
  const float* enc = (const float*)d_in[1];
  const float* vq  = (const float*)d_in[2];
  const float* nrg = (const float*)d_in[3];
  const float* nrb = (const float*)d_in[4];
  const float* nig = (const float*)d_in[5];
  const float* nib = (const float*)d_in[6];
  const float* qWr = (const float*)d_in[7];
  const float* qbr = (const float*)d_in[8];
  const float* qWi = (const float*)d_in[9];
  const float* qbi = (const float*)d_in[10];
  const float* gtw = (const float*)d_in[11];
  const float* gtb = (const float*)d_in[12];
  const float* aW  = (const float*)d_in[13];
  const float* ab  = (const float*)d_in[14];
  const float* dW  = (const float*)d_in[15];
  const float* db  = (const float*)d_in[16];
  const float* hb  = (const float*)d_in[17];
  const float* ig  = (const float*)d_in[18];
  char* ws = (char*)d_ws;
  float* out = (float*)d_out;
  hipLaunchKernelGGL(sacrsn_init, dim3(1), dim3(512), 0, stream, ws);
  hipLaunchKernelGGL(k_prepv, dim3(1024), dim3(256), 0, stream, vq, ws);
  hipLaunchKernelGGL(sacrsn_main, dim3(NBLK), dim3(NTHR), 0, stream,
                     x_seq, enc, vq, nrg, nrb, nig, nib, qWr, qbr, qWi, qbi,
                     gtw, gtb, aW, ab, hb, ig, out, ws);
  hipLaunchKernelGGL(k_prepd, dim3(1024), dim3(256), 0, stream, dW, ws);
  hipLaunchKernelGGL(k_dec, dim3(2048), dim3(256), 0, stream, db, out, ws);
}